// Round 12
// baseline (591.873 us; speedup 1.0000x reference)
//
#include <hip/hip_runtime.h>

constexpr int Bn = 8, Nn = 1024, Cn = 768, Hn = 12, Dn = 64;

typedef _Float16 f16x4 __attribute__((ext_vector_type(4)));
typedef _Float16 f16x8 __attribute__((ext_vector_type(8)));
typedef float    f32x4v __attribute__((ext_vector_type(4)));

__device__ __forceinline__ unsigned toOrd(float f) {
  unsigned u = __float_as_uint(f);
  return (u & 0x80000000u) ? ~u : (u | 0x80000000u);
}
__device__ __forceinline__ float invOrd(unsigned v) {
  unsigned b = (v & 0x80000000u) ? (v & 0x7FFFFFFFu) : ~v;
  return __uint_as_float(b);
}
// popcount of mask bits strictly below this lane (v_mbcnt pair)
__device__ __forceinline__ int lane_excl_cnt(unsigned long long m) {
  return __builtin_amdgcn_mbcnt_hi((unsigned)(m >> 32),
         __builtin_amdgcn_mbcnt_lo((unsigned)m, 0));
}

// ---- wave64 reductions via DPP ---------------------------------------------
__device__ __forceinline__ float wave_sum_f32(float x) {
  int xi = __float_as_int(x);
  x += __int_as_float(__builtin_amdgcn_update_dpp(0, xi, 0x111, 0xF, 0xF, false)); xi = __float_as_int(x);
  x += __int_as_float(__builtin_amdgcn_update_dpp(0, xi, 0x112, 0xF, 0xF, false)); xi = __float_as_int(x);
  x += __int_as_float(__builtin_amdgcn_update_dpp(0, xi, 0x114, 0xF, 0xF, false)); xi = __float_as_int(x);
  x += __int_as_float(__builtin_amdgcn_update_dpp(0, xi, 0x118, 0xF, 0xF, false)); xi = __float_as_int(x);
  x += __int_as_float(__builtin_amdgcn_update_dpp(0, xi, 0x142, 0xA, 0xF, false)); xi = __float_as_int(x);
  x += __int_as_float(__builtin_amdgcn_update_dpp(0, xi, 0x143, 0xC, 0xF, false));
  return __int_as_float(__builtin_amdgcn_readlane(__float_as_int(x), 63));
}
__device__ __forceinline__ unsigned wave_max_u32(unsigned x) {
  int xi = (int)x;
  x = max(x, (unsigned)__builtin_amdgcn_update_dpp(xi, xi, 0x111, 0xF, 0xF, false)); xi = (int)x;
  x = max(x, (unsigned)__builtin_amdgcn_update_dpp(xi, xi, 0x112, 0xF, 0xF, false)); xi = (int)x;
  x = max(x, (unsigned)__builtin_amdgcn_update_dpp(xi, xi, 0x114, 0xF, 0xF, false)); xi = (int)x;
  x = max(x, (unsigned)__builtin_amdgcn_update_dpp(xi, xi, 0x118, 0xF, 0xF, false)); xi = (int)x;
  x = max(x, (unsigned)__builtin_amdgcn_update_dpp(xi, xi, 0x142, 0xA, 0xF, false)); xi = (int)x;
  x = max(x, (unsigned)__builtin_amdgcn_update_dpp(xi, xi, 0x143, 0xC, 0xF, false));
  return (unsigned)__builtin_amdgcn_readlane((int)x, 63);
}
__device__ __forceinline__ unsigned wave_min_u32(unsigned x) {
  int xi = (int)x;
  x = min(x, (unsigned)__builtin_amdgcn_update_dpp(xi, xi, 0x111, 0xF, 0xF, false)); xi = (int)x;
  x = min(x, (unsigned)__builtin_amdgcn_update_dpp(xi, xi, 0x112, 0xF, 0xF, false)); xi = (int)x;
  x = min(x, (unsigned)__builtin_amdgcn_update_dpp(xi, xi, 0x114, 0xF, 0xF, false)); xi = (int)x;
  x = min(x, (unsigned)__builtin_amdgcn_update_dpp(xi, xi, 0x118, 0xF, 0xF, false)); xi = (int)x;
  x = min(x, (unsigned)__builtin_amdgcn_update_dpp(xi, xi, 0x142, 0xA, 0xF, false)); xi = (int)x;
  x = min(x, (unsigned)__builtin_amdgcn_update_dpp(xi, xi, 0x143, 0xC, 0xF, false));
  return (unsigned)__builtin_amdgcn_readlane((int)x, 63);
}

// ------- fused QKV GEMM: split-fp16 MFMA (3-term Markidis), M128 x N64 ------
__global__ __launch_bounds__(256) void qkv_gemm_mfma(
    const float* __restrict__ X, const float* __restrict__ W,
    const float* __restrict__ bias,
    _Float16* __restrict__ qhp, _Float16* __restrict__ qlp,
    _Float16* __restrict__ khp, _Float16* __restrict__ klp,
    float* __restrict__ vb)
{
  constexpr int LDH = 40; // fp16 row stride: 80B, 16B-aligned, 2-way banks
  __shared__ _Float16 AhH[128*LDH];
  __shared__ _Float16 AhL[128*LDH];
  __shared__ _Float16 BhH[64*LDH];
  __shared__ _Float16 BhL[64*LDH];
  int t = threadIdx.x;
  int wv = t >> 6, lane = t & 63;
  int quad = lane >> 4, l16 = lane & 15;
  int mt = blockIdx.x & 63, nt = blockIdx.x >> 6;
  int m0 = mt*128, n0 = nt*64;
  const float* Ap = X + (size_t)m0*768;
  const float* Bp = W + (size_t)n0*768;
  f32x4v acc1[2][4] = {};   // hi*hi
  f32x4v acc2[2][4] = {};   // 2048*(hi*lo + lo*hi)
  for (int k0 = 0; k0 < 768; k0 += 32) {
    float4 av[4]; float4 bv[2];
#pragma unroll
    for (int i = 0; i < 4; ++i) {
      int q = t + i*256;
      av[i] = *(const float4*)(Ap + (size_t)(q>>3)*768 + k0 + (q&7)*4);
    }
#pragma unroll
    for (int i = 0; i < 2; ++i) {
      int q = t + i*256;
      bv[i] = *(const float4*)(Bp + (size_t)(q>>3)*768 + k0 + (q&7)*4);
    }
    __syncthreads();
#pragma unroll
    for (int i = 0; i < 4; ++i) {
      int q = t + i*256;
      f16x4 h, l;
      h[0]=(_Float16)av[i].x; h[1]=(_Float16)av[i].y;
      h[2]=(_Float16)av[i].z; h[3]=(_Float16)av[i].w;
      l[0]=(_Float16)((av[i].x-(float)h[0])*2048.0f);
      l[1]=(_Float16)((av[i].y-(float)h[1])*2048.0f);
      l[2]=(_Float16)((av[i].z-(float)h[2])*2048.0f);
      l[3]=(_Float16)((av[i].w-(float)h[3])*2048.0f);
      *(f16x4*)(&AhH[(q>>3)*LDH + (q&7)*4]) = h;
      *(f16x4*)(&AhL[(q>>3)*LDH + (q&7)*4]) = l;
    }
#pragma unroll
    for (int i = 0; i < 2; ++i) {
      int q = t + i*256;
      f16x4 h, l;
      h[0]=(_Float16)bv[i].x; h[1]=(_Float16)bv[i].y;
      h[2]=(_Float16)bv[i].z; h[3]=(_Float16)bv[i].w;
      l[0]=(_Float16)((bv[i].x-(float)h[0])*2048.0f);
      l[1]=(_Float16)((bv[i].y-(float)h[1])*2048.0f);
      l[2]=(_Float16)((bv[i].z-(float)h[2])*2048.0f);
      l[3]=(_Float16)((bv[i].w-(float)h[3])*2048.0f);
      *(f16x4*)(&BhH[(q>>3)*LDH + (q&7)*4]) = h;
      *(f16x4*)(&BhL[(q>>3)*LDH + (q&7)*4]) = l;
    }
    __syncthreads();
    f16x8 bfh[4], bfl[4];
#pragma unroll
    for (int ni = 0; ni < 4; ++ni) {
      bfh[ni] = *(f16x8*)(&BhH[(ni*16+l16)*LDH + quad*8]);
      bfl[ni] = *(f16x8*)(&BhL[(ni*16+l16)*LDH + quad*8]);
    }
#pragma unroll
    for (int mi = 0; mi < 2; ++mi) {
      f16x8 afh = *(f16x8*)(&AhH[(wv*32+mi*16+l16)*LDH + quad*8]);
      f16x8 afl = *(f16x8*)(&AhL[(wv*32+mi*16+l16)*LDH + quad*8]);
#pragma unroll
      for (int ni = 0; ni < 4; ++ni) {
        acc1[mi][ni] = __builtin_amdgcn_mfma_f32_16x16x32_f16(afh, bfh[ni], acc1[mi][ni], 0, 0, 0);
        acc2[mi][ni] = __builtin_amdgcn_mfma_f32_16x16x32_f16(afh, bfl[ni], acc2[mi][ni], 0, 0, 0);
        acc2[mi][ni] = __builtin_amdgcn_mfma_f32_16x16x32_f16(afl, bfh[ni], acc2[mi][ni], 0, 0, 0);
      }
    }
  }
  int which = n0 / Cn;
  int rem0 = n0 - which*Cn;
  int h0 = rem0 >> 6;
  float sc = which == 0 ? 0.125f : 1.0f;
#pragma unroll
  for (int ni = 0; ni < 4; ++ni) {
    float bsv = bias[n0 + ni*16 + l16];
    int dd = (ni*16 + l16) & 63;
#pragma unroll
    for (int mi = 0; mi < 2; ++mi)
#pragma unroll
      for (int r = 0; r < 4; ++r) {
        int gm = m0 + wv*32 + mi*16 + quad*4 + r;
        int bbi = gm >> 10, nn = gm & 1023;
        size_t idx = (((size_t)(bbi*Hn + h0))*Nn + nn)*Dn + dd;
        float val = (acc1[mi][ni][r] + acc2[mi][ni][r] * (1.0f/2048.0f) + bsv) * sc;
        if (which == 2) {
          vb[idx] = val;
        } else {
          _Float16 hh = (_Float16)val;
          _Float16 ll = (_Float16)((val - (float)hh) * 2048.0f);
          if (which == 0) { qhp[idx] = hh; qlp[idx] = ll; }
          else            { khp[idx] = hh; klp[idx] = ll; }
        }
      }
  }
}

// ------- fp16 MFMA GEMM core (M128 x N64 tile, 4 waves, 16x16x32_f16) -------
template <typename Epi>
__device__ __forceinline__ void mfma_gemm_body(
    const float* __restrict__ Xp, const float* __restrict__ Wp, Epi epi)
{
  constexpr int LDH = 40;
  __shared__ _Float16 Ah[128*LDH];
  __shared__ _Float16 Bh[64*LDH];
  int t = threadIdx.x;
  int wv = t >> 6, lane = t & 63;
  int quad = lane >> 4, l16 = lane & 15;
  int mt = blockIdx.x & 63, nt = blockIdx.x >> 6;
  int m0 = mt*128, n0 = nt*64;
  f32x4v acc[2][4] = {};
  for (int k0 = 0; k0 < 768; k0 += 32) {
    float4 av[4]; float4 bv[2];
#pragma unroll
    for (int i = 0; i < 4; ++i) {
      int q = t + i*256;
      av[i] = *(const float4*)(Xp + (size_t)(m0+(q>>3))*768 + k0 + (q&7)*4);
    }
#pragma unroll
    for (int i = 0; i < 2; ++i) {
      int q = t + i*256;
      bv[i] = *(const float4*)(Wp + (size_t)(n0+(q>>3))*768 + k0 + (q&7)*4);
    }
    __syncthreads();
#pragma unroll
    for (int i = 0; i < 4; ++i) {
      int q = t + i*256;
      f16x4 h; h[0]=(_Float16)av[i].x; h[1]=(_Float16)av[i].y;
               h[2]=(_Float16)av[i].z; h[3]=(_Float16)av[i].w;
      *(f16x4*)(&Ah[(q>>3)*LDH + (q&7)*4]) = h;
    }
#pragma unroll
    for (int i = 0; i < 2; ++i) {
      int q = t + i*256;
      f16x4 h; h[0]=(_Float16)bv[i].x; h[1]=(_Float16)bv[i].y;
               h[2]=(_Float16)bv[i].z; h[3]=(_Float16)bv[i].w;
      *(f16x4*)(&Bh[(q>>3)*LDH + (q&7)*4]) = h;
    }
    __syncthreads();
    f16x8 bf[4], af;
#pragma unroll
    for (int ni = 0; ni < 4; ++ni)
      bf[ni] = *(f16x8*)(&Bh[(ni*16+l16)*LDH + quad*8]);
#pragma unroll
    for (int mi = 0; mi < 2; ++mi) {
      af = *(f16x8*)(&Ah[(wv*32+mi*16+l16)*LDH + quad*8]);
#pragma unroll
      for (int ni = 0; ni < 4; ++ni)
        acc[mi][ni] = __builtin_amdgcn_mfma_f32_16x16x32_f16(af, bf[ni], acc[mi][ni], 0, 0, 0);
    }
  }
#pragma unroll
  for (int mi = 0; mi < 2; ++mi)
#pragma unroll
    for (int ni = 0; ni < 4; ++ni)
#pragma unroll
      for (int r = 0; r < 4; ++r) {
        int gm = m0 + wv*32 + mi*16 + quad*4 + r;
        int gn = n0 + ni*16 + l16;
        epi(gm, gn, acc[mi][ni][r]);
      }
}

__global__ __launch_bounds__(256) void proj_mfma(
    const float* __restrict__ Xp, const float* __restrict__ Wp,
    const float* __restrict__ bias, float* __restrict__ Out)
{
  mfma_gemm_body(Xp, Wp, [=](int gm, int gn, float val) {
    Out[(size_t)gm*768 + gn] = val + bias[gn];
  });
}

// ---------------- Attention -------------------------------------------------
// Chunked score transpose (measured R10: occ 83%, attn 303us). launch_bounds
// 2nd arg: hipcc budgeted 32 VGPR at (512,8) => spill (+61MB WRITE_SIZE).
// (512,4) => 4 blocks/CU x 8 waves = 32 waves/CU => 64-VGPR budget, no spill;
// LDS (33.8KB) still caps at the same 4 blocks/CU.
__global__ __launch_bounds__(512, 4) void attn_kernel(
    const _Float16* __restrict__ qh, const _Float16* __restrict__ ql,
    const _Float16* __restrict__ kh, const _Float16* __restrict__ kl,
    const float* __restrict__ vB, const int* __restrict__ kptr,
    float* __restrict__ out)
{
  constexpr int G = 16, CAP = 128, CAPP = CAP + 4, LDB = 132;
  __shared__ float  Bx[2][G][LDB];     // 16896 B score-exchange chunks
  __shared__ float2 PairS[G][CAPP];    // 16896 B compacted (wgt, idx) lists

  int t = threadIdx.x;
  int bh = blockIdx.x >> 6;          // 0..95  (b*12+h)
  int qg = blockIdx.x & 63;
  int qbase = qg * G;
  int w = t >> 6, lane = t & 63;
  int quad = lane >> 4, l16 = lane & 15;

  const _Float16* QH = qh + (size_t)bh * Nn * Dn;
  const _Float16* QL = ql + (size_t)bh * Nn * Dn;
  const _Float16* KH = kh + (size_t)bh * Nn * Dn;
  const _Float16* KL = kl + (size_t)bh * Nn * Dn;
  const float*   Vbh = vB + (size_t)bh * Nn * Dn;

  int r0 = w*2, r1 = r0 + 1;
  unsigned u0[16], u1[16];

  // Q fragments (A operand), reused across all 8 k-tiles of this wave
  f16x8 aqh[2], aql[2];
  {
    size_t qoff = (size_t)(qbase + l16) * Dn + quad * 8;
#pragma unroll
    for (int c = 0; c < 2; ++c) {
      aqh[c] = *(const f16x8*)(QH + qoff + c*32);
      aql[c] = *(const f16x8*)(QL + qoff + c*32);
    }
  }
  // K fragments: depth-1 prefetch ping-pong; tile of round j = w + 8j
  f16x8 bhf[2][2], blf[2][2];
  {
    size_t koff = (size_t)(16*w + l16) * Dn + quad*8;
#pragma unroll
    for (int c = 0; c < 2; ++c) {
      bhf[0][c] = *(const f16x8*)(KH + koff + c*32);
      blf[0][c] = *(const f16x8*)(KL + koff + c*32);
    }
  }
#pragma unroll
  for (int j = 0; j < 8; ++j) {
    if (j < 7) {
      size_t koff = (size_t)(16*w + 128*(j+1) + l16) * Dn + quad*8;
#pragma unroll
      for (int c = 0; c < 2; ++c) {
        bhf[(j+1)&1][c] = *(const f16x8*)(KH + koff + c*32);
        blf[(j+1)&1][c] = *(const f16x8*)(KL + koff + c*32);
      }
    }
    int cb = j & 1;
    f32x4v a1 = {}, a2 = {};
    a1 = __builtin_amdgcn_mfma_f32_16x16x32_f16(aqh[0], bhf[cb][0], a1, 0,0,0);
    a1 = __builtin_amdgcn_mfma_f32_16x16x32_f16(aqh[1], bhf[cb][1], a1, 0,0,0);
    a2 = __builtin_amdgcn_mfma_f32_16x16x32_f16(aqh[0], blf[cb][0], a2, 0,0,0);
    a2 = __builtin_amdgcn_mfma_f32_16x16x32_f16(aqh[1], blf[cb][1], a2, 0,0,0);
    a2 = __builtin_amdgcn_mfma_f32_16x16x32_f16(aql[0], bhf[cb][0], a2, 0,0,0);
    a2 = __builtin_amdgcn_mfma_f32_16x16x32_f16(aql[1], bhf[cb][1], a2, 0,0,0);
    // write this round's 16-col slice: global col = 128j + (w*16 + l16)
#pragma unroll
    for (int r2 = 0; r2 < 4; ++r2)
      Bx[cb][quad*4 + r2][w*16 + l16] = a1[r2] + a2[r2] * (1.0f/2048.0f);
    __syncthreads();
    // read own 2 rows: u[2j] <- col lane+128j, u[2j+1] <- col lane+64+128j
    u0[2*j]   = toOrd(Bx[cb][r0][lane]);
    u0[2*j+1] = toOrd(Bx[cb][r0][lane + 64]);
    u1[2*j]   = toOrd(Bx[cb][r1][lane]);
    u1[2*j+1] = toOrd(Bx[cb][r1][lane + 64]);
  }

  int kval = *kptr;
  bool doSel = (kval > 0 && kval < Nn);

  unsigned mu0 = u0[0], mu1 = u1[0];
#pragma unroll
  for (int i = 1; i < 16; ++i) { mu0 = max(mu0, u0[i]); mu1 = max(mu1, u1[i]); }
  float m0 = invOrd(wave_max_u32(mu0));
  float m1 = invOrd(wave_max_u32(mu1));

  // ---- dual-row ballot-counted radix bisection for the k-th largest -------
  unsigned thr0 = 0u, thr1 = 0u;
  if (doSel) {
    unsigned res0 = 0u, res1 = 0u;
    bool done0 = false, done1 = false;
    for (int bit = 31; bit >= 0; --bit) {
      if (!done0) {
        unsigned cand = res0 | (1u << bit);
        int ct = 0;
#pragma unroll
        for (int i = 0; i < 16; ++i)
          ct += __popcll(__ballot(u0[i] >= cand));
        if (ct == kval) {
          unsigned mn = 0xFFFFFFFFu;
#pragma unroll
          for (int i = 0; i < 16; ++i)
            if (u0[i] >= cand && u0[i] < mn) mn = u0[i];
          res0 = wave_min_u32(mn);
          done0 = true;
        } else if (ct > kval) res0 = cand;
      }
      if (!done1) {
        unsigned cand = res1 | (1u << bit);
        int ct = 0;
#pragma unroll
        for (int i = 0; i < 16; ++i)
          ct += __popcll(__ballot(u1[i] >= cand));
        if (ct == kval) {
          unsigned mn = 0xFFFFFFFFu;
#pragma unroll
          for (int i = 0; i < 16; ++i)
            if (u1[i] >= cand && u1[i] < mn) mn = u1[i];
          res1 = wave_min_u32(mn);
          done1 = true;
        } else if (ct > kval) res1 = cand;
      }
      if (done0 && done1) break;
    }
    thr0 = res0; thr1 = res1;
  }

  // ---- dual-row exp + compaction into Pair lists --------------------------
  float2* Pair0 = &PairS[r0][0];
  float2* Pair1 = &PairS[r1][0];
  float Zl0 = 0.f, Zl1 = 0.f;
  int cnt0 = 0, cnt1 = 0;
#pragma unroll
  for (int i = 0; i < 16; ++i) {
    bool k0 = (u0[i] >= thr0);
    unsigned long long mk0 = __ballot(k0);
    if (k0) {
      float wgt = __expf(invOrd(u0[i]) - m0);
      Zl0 += wgt;
      int pos = cnt0 + lane_excl_cnt(mk0);
      if (pos < CAP) {
        float2 pr; pr.x = wgt; pr.y = __int_as_float(lane + 64*i);
        Pair0[pos] = pr;
      }
    }
    cnt0 += __popcll(mk0);
    bool k1 = (u1[i] >= thr1);
    unsigned long long mk1 = __ballot(k1);
    if (k1) {
      float wgt = __expf(invOrd(u1[i]) - m1);
      Zl1 += wgt;
      int pos = cnt1 + lane_excl_cnt(mk1);
      if (pos < CAP) {
        float2 pr; pr.x = wgt; pr.y = __int_as_float(lane + 64*i);
        Pair1[pos] = pr;
      }
    }
    cnt1 += __popcll(mk1);
  }
  float Z0 = wave_sum_f32(Zl0);
  float Z1 = wave_sum_f32(Zl1);

  // zero-pad 4 entries past each list so 4-wide PV needs no tail guards
  if (lane < 4) {
    float2 z; z.x = 0.f; z.y = __int_as_float(0);
    if (cnt0 <= CAP) Pair0[cnt0 + lane] = z;
    if (cnt1 <= CAP) Pair1[cnt1 + lane] = z;
  }

  // ---- PV ------------------------------------------------------------------
  float acc0 = 0.f, acc1 = 0.f;
  bool fast0 = (cnt0 <= CAP), fast1 = (cnt1 <= CAP);
  if (fast0 && fast1) {
    int nc = min(cnt0, cnt1);
    int i = 0;
    for (; i < nc; i += 4) {          // joint: 8 outstanding V-row loads
      float2 p00 = Pair0[i],   p01 = Pair0[i+1];
      float2 p02 = Pair0[i+2], p03 = Pair0[i+3];
      float2 p10 = Pair1[i],   p11 = Pair1[i+1];
      float2 p12 = Pair1[i+2], p13 = Pair1[i+3];
      float v00 = Vbh[(size_t)__float_as_int(p00.y)*Dn + lane];
      float v01 = Vbh[(size_t)__float_as_int(p01.y)*Dn + lane];
      float v02 = Vbh[(size_t)__float_as_int(p02.y)*Dn + lane];
      float v03 = Vbh[(size_t)__float_as_int(p03.y)*Dn + lane];
      float v10 = Vbh[(size_t)__float_as_int(p10.y)*Dn + lane];
      float v11 = Vbh[(size_t)__float_as_int(p11.y)*Dn + lane];
      float v12 = Vbh[(size_t)__float_as_int(p12.y)*Dn + lane];
      float v13 = Vbh[(size_t)__float_as_int(p13.y)*Dn + lane];
      acc0 = fmaf(p00.x, v00, acc0); acc0 = fmaf(p01.x, v01, acc0);
      acc0 = fmaf(p02.x, v02, acc0); acc0 = fmaf(p03.x, v03, acc0);
      acc1 = fmaf(p10.x, v10, acc1); acc1 = fmaf(p11.x, v11, acc1);
      acc1 = fmaf(p12.x, v12, acc1); acc1 = fmaf(p13.x, v13, acc1);
    }
    for (; i < cnt0; i += 4) {        // row0 tail
      float2 p0 = Pair0[i],   p1 = Pair0[i+1];
      float2 p2 = Pair0[i+2], p3 = Pair0[i+3];
      float v0 = Vbh[(size_t)__float_as_int(p0.y)*Dn + lane];
      float v1 = Vbh[(size_t)__float_as_int(p1.y)*Dn + lane];
      float v2 = Vbh[(size_t)__float_as_int(p2.y)*Dn + lane];
      float v3 = Vbh[(size_t)__float_as_int(p3.y)*Dn + lane];
      acc0 = fmaf(p0.x, v0, acc0); acc0 = fmaf(p1.x, v1, acc0);
      acc0 = fmaf(p2.x, v2, acc0); acc0 = fmaf(p3.x, v3, acc0);
    }
    for (; i < cnt1; i += 4) {        // row1 tail
      float2 p0 = Pair1[i],   p1 = Pair1[i+1];
      float2 p2 = Pair1[i+2], p3 = Pair1[i+3];
      float v0 = Vbh[(size_t)__float_as_int(p0.y)*Dn + lane];
      float v1 = Vbh[(size_t)__float_as_int(p1.y)*Dn + lane];
      float v2 = Vbh[(size_t)__float_as_int(p2.y)*Dn + lane];
      float v3 = Vbh[(size_t)__float_as_int(p3.y)*Dn + lane];
      acc1 = fmaf(p0.x, v0, acc1); acc1 = fmaf(p1.x, v1, acc1);
      acc1 = fmaf(p2.x, v2, acc1); acc1 = fmaf(p3.x, v3, acc1);
    }
  } else {
    // rare: oversize list (selection disabled or heavy ties). Weights are
    // re-derived from registers via shuffle; slow but tiny-LDS and correct.
    if (fast0) {
      for (int i = 0; i < cnt0; i += 4) {
        float2 p0 = Pair0[i],   p1 = Pair0[i+1];
        float2 p2 = Pair0[i+2], p3 = Pair0[i+3];
        float v0 = Vbh[(size_t)__float_as_int(p0.y)*Dn + lane];
        float v1 = Vbh[(size_t)__float_as_int(p1.y)*Dn + lane];
        float v2 = Vbh[(size_t)__float_as_int(p2.y)*Dn + lane];
        float v3 = Vbh[(size_t)__float_as_int(p3.y)*Dn + lane];
        acc0 = fmaf(p0.x, v0, acc0); acc0 = fmaf(p1.x, v1, acc0);
        acc0 = fmaf(p2.x, v2, acc0); acc0 = fmaf(p3.x, v3, acc0);
      }
    } else {
#pragma unroll
      for (int i = 0; i < 16; ++i) {
        float wbase = (u0[i] >= thr0) ? __expf(invOrd(u0[i]) - m0) : 0.f;
        for (int src = 0; src < 64; ++src) {
          float wgt = __shfl(wbase, src);
          if (wgt != 0.f)
            acc0 = fmaf(wgt, Vbh[(size_t)(src + 64*i)*Dn + lane], acc0);
        }
      }
    }
    if (fast1) {
      for (int i = 0; i < cnt1; i += 4) {
        float2 p0 = Pair1[i],   p1 = Pair1[i+1];
        float2 p2 = Pair1[i+2], p3 = Pair1[i+3];
        float v0 = Vbh[(size_t)__float_as_int(p0.y)*Dn + lane];
        float v1 = Vbh[(size_t)__float_as_int(p1.y)*Dn + lane];
        float v2 = Vbh[(size_t)__float_as_int(p2.y)*Dn + lane];
        float v3 = Vbh[(size_t)__float_as_int(p3.y)*Dn + lane];
        acc1 = fmaf(p0.x, v0, acc1); acc1 = fmaf(p1.x, v1, acc1);
        acc1 = fmaf(p2.x, v2, acc1); acc1 = fmaf(p3.x, v3, acc1);
      }
    } else {
#pragma unroll
      for (int i = 0; i < 16; ++i) {
        float wbase = (u1[i] >= thr1) ? __expf(invOrd(u1[i]) - m1) : 0.f;
        for (int src = 0; src < 64; ++src) {
          float wgt = __shfl(wbase, src);
          if (wgt != 0.f)
            acc1 = fmaf(wgt, Vbh[(size_t)(src + 64*i)*Dn + lane], acc1);
        }
      }
    }
  }

  int b = bh / Hn, h = bh - b*Hn;
  out[((size_t)(b*Nn + qbase + r0))*Cn + h*Dn + lane] = acc0 * (1.0f / Z0);
  out[((size_t)(b*Nn + qbase + r1))*Cn + h*Dn + lane] = acc1 * (1.0f / Z1);
}

extern "C" void kernel_launch(void* const* d_in, const int* in_sizes, int n_in,
                              void* d_out, int out_size, void* d_ws, size_t ws_size,
                              hipStream_t stream) {
  const float* x      = (const float*)d_in[0];
  const float* qkv_w  = (const float*)d_in[1];
  const float* qkv_b  = (const float*)d_in[2];
  const float* proj_w = (const float*)d_in[3];
  const float* proj_b = (const float*)d_in[4];
  const int*   kptr   = (const int*)d_in[5];

  const size_t sz = (size_t)Bn * Hn * Nn * Dn;   // 6291456 elements
  _Float16* qh = (_Float16*)d_ws;                // split-fp16 planes
  _Float16* ql = qh + sz;
  _Float16* kh = ql + sz;
  _Float16* kl = kh + sz;
  float* vbuf  = (float*)(kl + sz);
  float* att   = vbuf + sz;                      // (B,N,C)
  float* outp  = (float*)d_out;

  qkv_gemm_mfma<<<dim3(36*64), 256, 0, stream>>>(x, qkv_w, qkv_b,
                                                 qh, ql, kh, kl, vbuf);
  attn_kernel<<<dim3(Bn*Hn*(Nn/16)), 512, 0, stream>>>(qh, ql, kh, kl,
                                                       vbuf, kptr, att);
  proj_mfma<<<dim3(12*64), 256, 0, stream>>>(att, proj_w, proj_b, outp);
}

// Round 14
// 541.141 us; speedup vs baseline: 1.0937x; 1.0937x over previous
//
#include <hip/hip_runtime.h>

constexpr int Bn = 8, Nn = 1024, Cn = 768, Hn = 12, Dn = 64;

typedef _Float16 f16x4 __attribute__((ext_vector_type(4)));
typedef _Float16 f16x8 __attribute__((ext_vector_type(8)));
typedef float    f32x4v __attribute__((ext_vector_type(4)));

__device__ __forceinline__ unsigned toOrd(float f) {
  unsigned u = __float_as_uint(f);
  return (u & 0x80000000u) ? ~u : (u | 0x80000000u);
}
__device__ __forceinline__ float invOrd(unsigned v) {
  unsigned b = (v & 0x80000000u) ? (v & 0x7FFFFFFFu) : ~v;
  return __uint_as_float(b);
}
// popcount of mask bits strictly below this lane (v_mbcnt pair)
__device__ __forceinline__ int lane_excl_cnt(unsigned long long m) {
  return __builtin_amdgcn_mbcnt_hi((unsigned)(m >> 32),
         __builtin_amdgcn_mbcnt_lo((unsigned)m, 0));
}

// ---- wave64 reductions via DPP ---------------------------------------------
__device__ __forceinline__ float wave_sum_f32(float x) {
  int xi = __float_as_int(x);
  x += __int_as_float(__builtin_amdgcn_update_dpp(0, xi, 0x111, 0xF, 0xF, false)); xi = __float_as_int(x);
  x += __int_as_float(__builtin_amdgcn_update_dpp(0, xi, 0x112, 0xF, 0xF, false)); xi = __float_as_int(x);
  x += __int_as_float(__builtin_amdgcn_update_dpp(0, xi, 0x114, 0xF, 0xF, false)); xi = __float_as_int(x);
  x += __int_as_float(__builtin_amdgcn_update_dpp(0, xi, 0x118, 0xF, 0xF, false)); xi = __float_as_int(x);
  x += __int_as_float(__builtin_amdgcn_update_dpp(0, xi, 0x142, 0xA, 0xF, false)); xi = __float_as_int(x);
  x += __int_as_float(__builtin_amdgcn_update_dpp(0, xi, 0x143, 0xC, 0xF, false));
  return __int_as_float(__builtin_amdgcn_readlane(__float_as_int(x), 63));
}
__device__ __forceinline__ unsigned wave_max_u32(unsigned x) {
  int xi = (int)x;
  x = max(x, (unsigned)__builtin_amdgcn_update_dpp(xi, xi, 0x111, 0xF, 0xF, false)); xi = (int)x;
  x = max(x, (unsigned)__builtin_amdgcn_update_dpp(xi, xi, 0x112, 0xF, 0xF, false)); xi = (int)x;
  x = max(x, (unsigned)__builtin_amdgcn_update_dpp(xi, xi, 0x114, 0xF, 0xF, false)); xi = (int)x;
  x = max(x, (unsigned)__builtin_amdgcn_update_dpp(xi, xi, 0x118, 0xF, 0xF, false)); xi = (int)x;
  x = max(x, (unsigned)__builtin_amdgcn_update_dpp(xi, xi, 0x142, 0xA, 0xF, false)); xi = (int)x;
  x = max(x, (unsigned)__builtin_amdgcn_update_dpp(xi, xi, 0x143, 0xC, 0xF, false));
  return (unsigned)__builtin_amdgcn_readlane((int)x, 63);
}
__device__ __forceinline__ unsigned wave_min_u32(unsigned x) {
  int xi = (int)x;
  x = min(x, (unsigned)__builtin_amdgcn_update_dpp(xi, xi, 0x111, 0xF, 0xF, false)); xi = (int)x;
  x = min(x, (unsigned)__builtin_amdgcn_update_dpp(xi, xi, 0x112, 0xF, 0xF, false)); xi = (int)x;
  x = min(x, (unsigned)__builtin_amdgcn_update_dpp(xi, xi, 0x114, 0xF, 0xF, false)); xi = (int)x;
  x = min(x, (unsigned)__builtin_amdgcn_update_dpp(xi, xi, 0x118, 0xF, 0xF, false)); xi = (int)x;
  x = min(x, (unsigned)__builtin_amdgcn_update_dpp(xi, xi, 0x142, 0xA, 0xF, false)); xi = (int)x;
  x = min(x, (unsigned)__builtin_amdgcn_update_dpp(xi, xi, 0x143, 0xC, 0xF, false));
  return (unsigned)__builtin_amdgcn_readlane((int)x, 63);
}

// ------- fused QKV GEMM: split-fp16 MFMA (3-term Markidis), M128 x N64 ------
__global__ __launch_bounds__(256) void qkv_gemm_mfma(
    const float* __restrict__ X, const float* __restrict__ W,
    const float* __restrict__ bias,
    _Float16* __restrict__ qhp, _Float16* __restrict__ qlp,
    _Float16* __restrict__ khp, _Float16* __restrict__ klp,
    float* __restrict__ vb)
{
  constexpr int LDH = 40; // fp16 row stride: 80B, 16B-aligned, 2-way banks
  __shared__ _Float16 AhH[128*LDH];
  __shared__ _Float16 AhL[128*LDH];
  __shared__ _Float16 BhH[64*LDH];
  __shared__ _Float16 BhL[64*LDH];
  int t = threadIdx.x;
  int wv = t >> 6, lane = t & 63;
  int quad = lane >> 4, l16 = lane & 15;
  int mt = blockIdx.x & 63, nt = blockIdx.x >> 6;
  int m0 = mt*128, n0 = nt*64;
  const float* Ap = X + (size_t)m0*768;
  const float* Bp = W + (size_t)n0*768;
  f32x4v acc1[2][4] = {};   // hi*hi
  f32x4v acc2[2][4] = {};   // 2048*(hi*lo + lo*hi)
  for (int k0 = 0; k0 < 768; k0 += 32) {
    float4 av[4]; float4 bv[2];
#pragma unroll
    for (int i = 0; i < 4; ++i) {
      int q = t + i*256;
      av[i] = *(const float4*)(Ap + (size_t)(q>>3)*768 + k0 + (q&7)*4);
    }
#pragma unroll
    for (int i = 0; i < 2; ++i) {
      int q = t + i*256;
      bv[i] = *(const float4*)(Bp + (size_t)(q>>3)*768 + k0 + (q&7)*4);
    }
    __syncthreads();
#pragma unroll
    for (int i = 0; i < 4; ++i) {
      int q = t + i*256;
      f16x4 h, l;
      h[0]=(_Float16)av[i].x; h[1]=(_Float16)av[i].y;
      h[2]=(_Float16)av[i].z; h[3]=(_Float16)av[i].w;
      l[0]=(_Float16)((av[i].x-(float)h[0])*2048.0f);
      l[1]=(_Float16)((av[i].y-(float)h[1])*2048.0f);
      l[2]=(_Float16)((av[i].z-(float)h[2])*2048.0f);
      l[3]=(_Float16)((av[i].w-(float)h[3])*2048.0f);
      *(f16x4*)(&AhH[(q>>3)*LDH + (q&7)*4]) = h;
      *(f16x4*)(&AhL[(q>>3)*LDH + (q&7)*4]) = l;
    }
#pragma unroll
    for (int i = 0; i < 2; ++i) {
      int q = t + i*256;
      f16x4 h, l;
      h[0]=(_Float16)bv[i].x; h[1]=(_Float16)bv[i].y;
      h[2]=(_Float16)bv[i].z; h[3]=(_Float16)bv[i].w;
      l[0]=(_Float16)((bv[i].x-(float)h[0])*2048.0f);
      l[1]=(_Float16)((bv[i].y-(float)h[1])*2048.0f);
      l[2]=(_Float16)((bv[i].z-(float)h[2])*2048.0f);
      l[3]=(_Float16)((bv[i].w-(float)h[3])*2048.0f);
      *(f16x4*)(&BhH[(q>>3)*LDH + (q&7)*4]) = h;
      *(f16x4*)(&BhL[(q>>3)*LDH + (q&7)*4]) = l;
    }
    __syncthreads();
    f16x8 bfh[4], bfl[4];
#pragma unroll
    for (int ni = 0; ni < 4; ++ni) {
      bfh[ni] = *(f16x8*)(&BhH[(ni*16+l16)*LDH + quad*8]);
      bfl[ni] = *(f16x8*)(&BhL[(ni*16+l16)*LDH + quad*8]);
    }
#pragma unroll
    for (int mi = 0; mi < 2; ++mi) {
      f16x8 afh = *(f16x8*)(&AhH[(wv*32+mi*16+l16)*LDH + quad*8]);
      f16x8 afl = *(f16x8*)(&AhL[(wv*32+mi*16+l16)*LDH + quad*8]);
#pragma unroll
      for (int ni = 0; ni < 4; ++ni) {
        acc1[mi][ni] = __builtin_amdgcn_mfma_f32_16x16x32_f16(afh, bfh[ni], acc1[mi][ni], 0, 0, 0);
        acc2[mi][ni] = __builtin_amdgcn_mfma_f32_16x16x32_f16(afh, bfl[ni], acc2[mi][ni], 0, 0, 0);
        acc2[mi][ni] = __builtin_amdgcn_mfma_f32_16x16x32_f16(afl, bfh[ni], acc2[mi][ni], 0, 0, 0);
      }
    }
  }
  int which = n0 / Cn;
  int rem0 = n0 - which*Cn;
  int h0 = rem0 >> 6;
  float sc = which == 0 ? 0.125f : 1.0f;
#pragma unroll
  for (int ni = 0; ni < 4; ++ni) {
    float bsv = bias[n0 + ni*16 + l16];
    int dd = (ni*16 + l16) & 63;
#pragma unroll
    for (int mi = 0; mi < 2; ++mi)
#pragma unroll
      for (int r = 0; r < 4; ++r) {
        int gm = m0 + wv*32 + mi*16 + quad*4 + r;
        int bbi = gm >> 10, nn = gm & 1023;
        size_t idx = (((size_t)(bbi*Hn + h0))*Nn + nn)*Dn + dd;
        float val = (acc1[mi][ni][r] + acc2[mi][ni][r] * (1.0f/2048.0f) + bsv) * sc;
        if (which == 2) {
          vb[idx] = val;
        } else {
          _Float16 hh = (_Float16)val;
          _Float16 ll = (_Float16)((val - (float)hh) * 2048.0f);
          if (which == 0) { qhp[idx] = hh; qlp[idx] = ll; }
          else            { khp[idx] = hh; klp[idx] = ll; }
        }
      }
  }
}

// ------- fp16 MFMA GEMM core (M128 x N64 tile, 4 waves, 16x16x32_f16) -------
template <typename Epi>
__device__ __forceinline__ void mfma_gemm_body(
    const float* __restrict__ Xp, const float* __restrict__ Wp, Epi epi)
{
  constexpr int LDH = 40;
  __shared__ _Float16 Ah[128*LDH];
  __shared__ _Float16 Bh[64*LDH];
  int t = threadIdx.x;
  int wv = t >> 6, lane = t & 63;
  int quad = lane >> 4, l16 = lane & 15;
  int mt = blockIdx.x & 63, nt = blockIdx.x >> 6;
  int m0 = mt*128, n0 = nt*64;
  f32x4v acc[2][4] = {};
  for (int k0 = 0; k0 < 768; k0 += 32) {
    float4 av[4]; float4 bv[2];
#pragma unroll
    for (int i = 0; i < 4; ++i) {
      int q = t + i*256;
      av[i] = *(const float4*)(Xp + (size_t)(m0+(q>>3))*768 + k0 + (q&7)*4);
    }
#pragma unroll
    for (int i = 0; i < 2; ++i) {
      int q = t + i*256;
      bv[i] = *(const float4*)(Wp + (size_t)(n0+(q>>3))*768 + k0 + (q&7)*4);
    }
    __syncthreads();
#pragma unroll
    for (int i = 0; i < 4; ++i) {
      int q = t + i*256;
      f16x4 h; h[0]=(_Float16)av[i].x; h[1]=(_Float16)av[i].y;
               h[2]=(_Float16)av[i].z; h[3]=(_Float16)av[i].w;
      *(f16x4*)(&Ah[(q>>3)*LDH + (q&7)*4]) = h;
    }
#pragma unroll
    for (int i = 0; i < 2; ++i) {
      int q = t + i*256;
      f16x4 h; h[0]=(_Float16)bv[i].x; h[1]=(_Float16)bv[i].y;
               h[2]=(_Float16)bv[i].z; h[3]=(_Float16)bv[i].w;
      *(f16x4*)(&Bh[(q>>3)*LDH + (q&7)*4]) = h;
    }
    __syncthreads();
    f16x8 bf[4], af;
#pragma unroll
    for (int ni = 0; ni < 4; ++ni)
      bf[ni] = *(f16x8*)(&Bh[(ni*16+l16)*LDH + quad*8]);
#pragma unroll
    for (int mi = 0; mi < 2; ++mi) {
      af = *(f16x8*)(&Ah[(wv*32+mi*16+l16)*LDH + quad*8]);
#pragma unroll
      for (int ni = 0; ni < 4; ++ni)
        acc[mi][ni] = __builtin_amdgcn_mfma_f32_16x16x32_f16(af, bf[ni], acc[mi][ni], 0, 0, 0);
    }
  }
#pragma unroll
  for (int mi = 0; mi < 2; ++mi)
#pragma unroll
    for (int ni = 0; ni < 4; ++ni)
#pragma unroll
      for (int r = 0; r < 4; ++r) {
        int gm = m0 + wv*32 + mi*16 + quad*4 + r;
        int gn = n0 + ni*16 + l16;
        epi(gm, gn, acc[mi][ni][r]);
      }
}

__global__ __launch_bounds__(256) void proj_mfma(
    const float* __restrict__ Xp, const float* __restrict__ Wp,
    const float* __restrict__ bias, float* __restrict__ Out)
{
  mfma_gemm_body(Xp, Wp, [=](int gm, int gn, float val) {
    Out[(size_t)gm*768 + gn] = val + bias[gn];
  });
}

// ---------------- Attention -------------------------------------------------
// Measured: (512,8)/32-VGPR+spill @83% occ = 303us BEATS (512,4)/44-VGPR
// no-spill @45% occ = 367us -> occupancy dominates. Keep (512,8); cut spill
// volume within the 32-VGPR budget by single-buffering the K fragments
// (frees 8 regs during QK phase; 8 waves/SIMD already hide global latency).
// MFMA order and Bx LDS ping-pong unchanged -> scores bit-identical.
__global__ __launch_bounds__(512, 8) void attn_kernel(
    const _Float16* __restrict__ qh, const _Float16* __restrict__ ql,
    const _Float16* __restrict__ kh, const _Float16* __restrict__ kl,
    const float* __restrict__ vB, const int* __restrict__ kptr,
    float* __restrict__ out)
{
  constexpr int G = 16, CAP = 128, CAPP = CAP + 4, LDB = 132;
  __shared__ float  Bx[2][G][LDB];     // 16896 B score-exchange chunks
  __shared__ float2 PairS[G][CAPP];    // 16896 B compacted (wgt, idx) lists

  int t = threadIdx.x;
  int bh = blockIdx.x >> 6;          // 0..95  (b*12+h)
  int qg = blockIdx.x & 63;
  int qbase = qg * G;
  int w = t >> 6, lane = t & 63;
  int quad = lane >> 4, l16 = lane & 15;

  const _Float16* QH = qh + (size_t)bh * Nn * Dn;
  const _Float16* QL = ql + (size_t)bh * Nn * Dn;
  const _Float16* KH = kh + (size_t)bh * Nn * Dn;
  const _Float16* KL = kl + (size_t)bh * Nn * Dn;
  const float*   Vbh = vB + (size_t)bh * Nn * Dn;

  int r0 = w*2, r1 = r0 + 1;
  unsigned u0[16], u1[16];

  // Q fragments (A operand), reused across all 8 k-tiles of this wave
  f16x8 aqh[2], aql[2];
  {
    size_t qoff = (size_t)(qbase + l16) * Dn + quad * 8;
#pragma unroll
    for (int c = 0; c < 2; ++c) {
      aqh[c] = *(const f16x8*)(QH + qoff + c*32);
      aql[c] = *(const f16x8*)(QL + qoff + c*32);
    }
  }
  // K fragments: single-buffered (reg-pressure cut; TLP hides the latency)
#pragma unroll
  for (int j = 0; j < 8; ++j) {
    f16x8 kfh[2], kfl[2];
    {
      size_t koff = (size_t)(16*w + 128*j + l16) * Dn + quad*8;
#pragma unroll
      for (int c = 0; c < 2; ++c) {
        kfh[c] = *(const f16x8*)(KH + koff + c*32);
        kfl[c] = *(const f16x8*)(KL + koff + c*32);
      }
    }
    int cb = j & 1;
    f32x4v a1 = {}, a2 = {};
    a1 = __builtin_amdgcn_mfma_f32_16x16x32_f16(aqh[0], kfh[0], a1, 0,0,0);
    a1 = __builtin_amdgcn_mfma_f32_16x16x32_f16(aqh[1], kfh[1], a1, 0,0,0);
    a2 = __builtin_amdgcn_mfma_f32_16x16x32_f16(aqh[0], kfl[0], a2, 0,0,0);
    a2 = __builtin_amdgcn_mfma_f32_16x16x32_f16(aqh[1], kfl[1], a2, 0,0,0);
    a2 = __builtin_amdgcn_mfma_f32_16x16x32_f16(aql[0], kfh[0], a2, 0,0,0);
    a2 = __builtin_amdgcn_mfma_f32_16x16x32_f16(aql[1], kfh[1], a2, 0,0,0);
    // write this round's 16-col slice: global col = 128j + (w*16 + l16)
#pragma unroll
    for (int r2 = 0; r2 < 4; ++r2)
      Bx[cb][quad*4 + r2][w*16 + l16] = a1[r2] + a2[r2] * (1.0f/2048.0f);
    __syncthreads();
    // read own 2 rows: u[2j] <- col lane+128j, u[2j+1] <- col lane+64+128j
    u0[2*j]   = toOrd(Bx[cb][r0][lane]);
    u0[2*j+1] = toOrd(Bx[cb][r0][lane + 64]);
    u1[2*j]   = toOrd(Bx[cb][r1][lane]);
    u1[2*j+1] = toOrd(Bx[cb][r1][lane + 64]);
  }

  int kval = *kptr;
  bool doSel = (kval > 0 && kval < Nn);

  unsigned mu0 = u0[0], mu1 = u1[0];
#pragma unroll
  for (int i = 1; i < 16; ++i) { mu0 = max(mu0, u0[i]); mu1 = max(mu1, u1[i]); }
  float m0 = invOrd(wave_max_u32(mu0));
  float m1 = invOrd(wave_max_u32(mu1));

  // ---- dual-row ballot-counted radix bisection for the k-th largest -------
  unsigned thr0 = 0u, thr1 = 0u;
  if (doSel) {
    unsigned res0 = 0u, res1 = 0u;
    bool done0 = false, done1 = false;
    for (int bit = 31; bit >= 0; --bit) {
      if (!done0) {
        unsigned cand = res0 | (1u << bit);
        int ct = 0;
#pragma unroll
        for (int i = 0; i < 16; ++i)
          ct += __popcll(__ballot(u0[i] >= cand));
        if (ct == kval) {
          unsigned mn = 0xFFFFFFFFu;
#pragma unroll
          for (int i = 0; i < 16; ++i)
            if (u0[i] >= cand && u0[i] < mn) mn = u0[i];
          res0 = wave_min_u32(mn);
          done0 = true;
        } else if (ct > kval) res0 = cand;
      }
      if (!done1) {
        unsigned cand = res1 | (1u << bit);
        int ct = 0;
#pragma unroll
        for (int i = 0; i < 16; ++i)
          ct += __popcll(__ballot(u1[i] >= cand));
        if (ct == kval) {
          unsigned mn = 0xFFFFFFFFu;
#pragma unroll
          for (int i = 0; i < 16; ++i)
            if (u1[i] >= cand && u1[i] < mn) mn = u1[i];
          res1 = wave_min_u32(mn);
          done1 = true;
        } else if (ct > kval) res1 = cand;
      }
      if (done0 && done1) break;
    }
    thr0 = res0; thr1 = res1;
  }

  // ---- dual-row exp + compaction into Pair lists --------------------------
  float2* Pair0 = &PairS[r0][0];
  float2* Pair1 = &PairS[r1][0];
  float Zl0 = 0.f, Zl1 = 0.f;
  int cnt0 = 0, cnt1 = 0;
#pragma unroll
  for (int i = 0; i < 16; ++i) {
    bool k0 = (u0[i] >= thr0);
    unsigned long long mk0 = __ballot(k0);
    if (k0) {
      float wgt = __expf(invOrd(u0[i]) - m0);
      Zl0 += wgt;
      int pos = cnt0 + lane_excl_cnt(mk0);
      if (pos < CAP) {
        float2 pr; pr.x = wgt; pr.y = __int_as_float(lane + 64*i);
        Pair0[pos] = pr;
      }
    }
    cnt0 += __popcll(mk0);
    bool k1 = (u1[i] >= thr1);
    unsigned long long mk1 = __ballot(k1);
    if (k1) {
      float wgt = __expf(invOrd(u1[i]) - m1);
      Zl1 += wgt;
      int pos = cnt1 + lane_excl_cnt(mk1);
      if (pos < CAP) {
        float2 pr; pr.x = wgt; pr.y = __int_as_float(lane + 64*i);
        Pair1[pos] = pr;
      }
    }
    cnt1 += __popcll(mk1);
  }
  float Z0 = wave_sum_f32(Zl0);
  float Z1 = wave_sum_f32(Zl1);

  // zero-pad 4 entries past each list so 4-wide PV needs no tail guards
  if (lane < 4) {
    float2 z; z.x = 0.f; z.y = __int_as_float(0);
    if (cnt0 <= CAP) Pair0[cnt0 + lane] = z;
    if (cnt1 <= CAP) Pair1[cnt1 + lane] = z;
  }

  // ---- PV ------------------------------------------------------------------
  float acc0 = 0.f, acc1 = 0.f;
  bool fast0 = (cnt0 <= CAP), fast1 = (cnt1 <= CAP);
  if (fast0 && fast1) {
    int nc = min(cnt0, cnt1);
    int i = 0;
    for (; i < nc; i += 4) {          // joint: 8 outstanding V-row loads
      float2 p00 = Pair0[i],   p01 = Pair0[i+1];
      float2 p02 = Pair0[i+2], p03 = Pair0[i+3];
      float2 p10 = Pair1[i],   p11 = Pair1[i+1];
      float2 p12 = Pair1[i+2], p13 = Pair1[i+3];
      float v00 = Vbh[(size_t)__float_as_int(p00.y)*Dn + lane];
      float v01 = Vbh[(size_t)__float_as_int(p01.y)*Dn + lane];
      float v02 = Vbh[(size_t)__float_as_int(p02.y)*Dn + lane];
      float v03 = Vbh[(size_t)__float_as_int(p03.y)*Dn + lane];
      float v10 = Vbh[(size_t)__float_as_int(p10.y)*Dn + lane];
      float v11 = Vbh[(size_t)__float_as_int(p11.y)*Dn + lane];
      float v12 = Vbh[(size_t)__float_as_int(p12.y)*Dn + lane];
      float v13 = Vbh[(size_t)__float_as_int(p13.y)*Dn + lane];
      acc0 = fmaf(p00.x, v00, acc0); acc0 = fmaf(p01.x, v01, acc0);
      acc0 = fmaf(p02.x, v02, acc0); acc0 = fmaf(p03.x, v03, acc0);
      acc1 = fmaf(p10.x, v10, acc1); acc1 = fmaf(p11.x, v11, acc1);
      acc1 = fmaf(p12.x, v12, acc1); acc1 = fmaf(p13.x, v13, acc1);
    }
    for (; i < cnt0; i += 4) {        // row0 tail
      float2 p0 = Pair0[i],   p1 = Pair0[i+1];
      float2 p2 = Pair0[i+2], p3 = Pair0[i+3];
      float v0 = Vbh[(size_t)__float_as_int(p0.y)*Dn + lane];
      float v1 = Vbh[(size_t)__float_as_int(p1.y)*Dn + lane];
      float v2 = Vbh[(size_t)__float_as_int(p2.y)*Dn + lane];
      float v3 = Vbh[(size_t)__float_as_int(p3.y)*Dn + lane];
      acc0 = fmaf(p0.x, v0, acc0); acc0 = fmaf(p1.x, v1, acc0);
      acc0 = fmaf(p2.x, v2, acc0); acc0 = fmaf(p3.x, v3, acc0);
    }
    for (; i < cnt1; i += 4) {        // row1 tail
      float2 p0 = Pair1[i],   p1 = Pair1[i+1];
      float2 p2 = Pair1[i+2], p3 = Pair1[i+3];
      float v0 = Vbh[(size_t)__float_as_int(p0.y)*Dn + lane];
      float v1 = Vbh[(size_t)__float_as_int(p1.y)*Dn + lane];
      float v2 = Vbh[(size_t)__float_as_int(p2.y)*Dn + lane];
      float v3 = Vbh[(size_t)__float_as_int(p3.y)*Dn + lane];
      acc1 = fmaf(p0.x, v0, acc1); acc1 = fmaf(p1.x, v1, acc1);
      acc1 = fmaf(p2.x, v2, acc1); acc1 = fmaf(p3.x, v3, acc1);
    }
  } else {
    // rare: oversize list (selection disabled or heavy ties). Weights are
    // re-derived from registers via shuffle; slow but tiny-LDS and correct.
    if (fast0) {
      for (int i = 0; i < cnt0; i += 4) {
        float2 p0 = Pair0[i],   p1 = Pair0[i+1];
        float2 p2 = Pair0[i+2], p3 = Pair0[i+3];
        float v0 = Vbh[(size_t)__float_as_int(p0.y)*Dn + lane];
        float v1 = Vbh[(size_t)__float_as_int(p1.y)*Dn + lane];
        float v2 = Vbh[(size_t)__float_as_int(p2.y)*Dn + lane];
        float v3 = Vbh[(size_t)__float_as_int(p3.y)*Dn + lane];
        acc0 = fmaf(p0.x, v0, acc0); acc0 = fmaf(p1.x, v1, acc0);
        acc0 = fmaf(p2.x, v2, acc0); acc0 = fmaf(p3.x, v3, acc0);
      }
    } else {
#pragma unroll
      for (int i = 0; i < 16; ++i) {
        float wbase = (u0[i] >= thr0) ? __expf(invOrd(u0[i]) - m0) : 0.f;
        for (int src = 0; src < 64; ++src) {
          float wgt = __shfl(wbase, src);
          if (wgt != 0.f)
            acc0 = fmaf(wgt, Vbh[(size_t)(src + 64*i)*Dn + lane], acc0);
        }
      }
    }
    if (fast1) {
      for (int i = 0; i < cnt1; i += 4) {
        float2 p0 = Pair1[i],   p1 = Pair1[i+1];
        float2 p2 = Pair1[i+2], p3 = Pair1[i+3];
        float v0 = Vbh[(size_t)__float_as_int(p0.y)*Dn + lane];
        float v1 = Vbh[(size_t)__float_as_int(p1.y)*Dn + lane];
        float v2 = Vbh[(size_t)__float_as_int(p2.y)*Dn + lane];
        float v3 = Vbh[(size_t)__float_as_int(p3.y)*Dn + lane];
        acc1 = fmaf(p0.x, v0, acc1); acc1 = fmaf(p1.x, v1, acc1);
        acc1 = fmaf(p2.x, v2, acc1); acc1 = fmaf(p3.x, v3, acc1);
      }
    } else {
#pragma unroll
      for (int i = 0; i < 16; ++i) {
        float wbase = (u1[i] >= thr1) ? __expf(invOrd(u1[i]) - m1) : 0.f;
        for (int src = 0; src < 64; ++src) {
          float wgt = __shfl(wbase, src);
          if (wgt != 0.f)
            acc1 = fmaf(wgt, Vbh[(size_t)(src + 64*i)*Dn + lane], acc1);
        }
      }
    }
  }

  int b = bh / Hn, h = bh - b*Hn;
  out[((size_t)(b*Nn + qbase + r0))*Cn + h*Dn + lane] = acc0 * (1.0f / Z0);
  out[((size_t)(b*Nn + qbase + r1))*Cn + h*Dn + lane] = acc1 * (1.0f / Z1);
}

extern "C" void kernel_launch(void* const* d_in, const int* in_sizes, int n_in,
                              void* d_out, int out_size, void* d_ws, size_t ws_size,
                              hipStream_t stream) {
  const float* x      = (const float*)d_in[0];
  const float* qkv_w  = (const float*)d_in[1];
  const float* qkv_b  = (const float*)d_in[2];
  const float* proj_w = (const float*)d_in[3];
  const float* proj_b = (const float*)d_in[4];
  const int*   kptr   = (const int*)d_in[5];

  const size_t sz = (size_t)Bn * Hn * Nn * Dn;   // 6291456 elements
  _Float16* qh = (_Float16*)d_ws;                // split-fp16 planes
  _Float16* ql = qh + sz;
  _Float16* kh = ql + sz;
  _Float16* kl = kh + sz;
  float* vbuf  = (float*)(kl + sz);
  float* att   = vbuf + sz;                      // (B,N,C)
  float* outp  = (float*)d_out;

  qkv_gemm_mfma<<<dim3(36*64), 256, 0, stream>>>(x, qkv_w, qkv_b,
                                                 qh, ql, kh, kl, vbuf);
  attn_kernel<<<dim3(Bn*Hn*(Nn/16)), 512, 0, stream>>>(qh, ql, kh, kl,
                                                       vbuf, kptr, att);
  proj_mfma<<<dim3(12*64), 256, 0, stream>>>(att, proj_w, proj_b, outp);
}

// Round 17
// 519.457 us; speedup vs baseline: 1.1394x; 1.0417x over previous
//
#include <hip/hip_runtime.h>

constexpr int Bn = 8, Nn = 1024, Cn = 768, Hn = 12, Dn = 64;

typedef _Float16 f16x4 __attribute__((ext_vector_type(4)));
typedef _Float16 f16x8 __attribute__((ext_vector_type(8)));
typedef float    f32x4v __attribute__((ext_vector_type(4)));

__device__ __forceinline__ unsigned toOrd(float f) {
  unsigned u = __float_as_uint(f);
  return (u & 0x80000000u) ? ~u : (u | 0x80000000u);
}
__device__ __forceinline__ float invOrd(unsigned v) {
  unsigned b = (v & 0x80000000u) ? (v & 0x7FFFFFFFu) : ~v;
  return __uint_as_float(b);
}
// popcount of mask bits strictly below this lane (v_mbcnt pair)
__device__ __forceinline__ int lane_excl_cnt(unsigned long long m) {
  return __builtin_amdgcn_mbcnt_hi((unsigned)(m >> 32),
         __builtin_amdgcn_mbcnt_lo((unsigned)m, 0));
}

// ---- wave64 reductions via DPP ---------------------------------------------
__device__ __forceinline__ float wave_sum_f32(float x) {
  int xi = __float_as_int(x);
  x += __int_as_float(__builtin_amdgcn_update_dpp(0, xi, 0x111, 0xF, 0xF, false)); xi = __float_as_int(x);
  x += __int_as_float(__builtin_amdgcn_update_dpp(0, xi, 0x112, 0xF, 0xF, false)); xi = __float_as_int(x);
  x += __int_as_float(__builtin_amdgcn_update_dpp(0, xi, 0x114, 0xF, 0xF, false)); xi = __float_as_int(x);
  x += __int_as_float(__builtin_amdgcn_update_dpp(0, xi, 0x118, 0xF, 0xF, false)); xi = __float_as_int(x);
  x += __int_as_float(__builtin_amdgcn_update_dpp(0, xi, 0x142, 0xA, 0xF, false)); xi = __float_as_int(x);
  x += __int_as_float(__builtin_amdgcn_update_dpp(0, xi, 0x143, 0xC, 0xF, false));
  return __int_as_float(__builtin_amdgcn_readlane(__float_as_int(x), 63));
}
__device__ __forceinline__ unsigned wave_max_u32(unsigned x) {
  int xi = (int)x;
  x = max(x, (unsigned)__builtin_amdgcn_update_dpp(xi, xi, 0x111, 0xF, 0xF, false)); xi = (int)x;
  x = max(x, (unsigned)__builtin_amdgcn_update_dpp(xi, xi, 0x112, 0xF, 0xF, false)); xi = (int)x;
  x = max(x, (unsigned)__builtin_amdgcn_update_dpp(xi, xi, 0x114, 0xF, 0xF, false)); xi = (int)x;
  x = max(x, (unsigned)__builtin_amdgcn_update_dpp(xi, xi, 0x118, 0xF, 0xF, false)); xi = (int)x;
  x = max(x, (unsigned)__builtin_amdgcn_update_dpp(xi, xi, 0x142, 0xA, 0xF, false)); xi = (int)x;
  x = max(x, (unsigned)__builtin_amdgcn_update_dpp(xi, xi, 0x143, 0xC, 0xF, false));
  return (unsigned)__builtin_amdgcn_readlane((int)x, 63);
}
__device__ __forceinline__ unsigned wave_min_u32(unsigned x) {
  int xi = (int)x;
  x = min(x, (unsigned)__builtin_amdgcn_update_dpp(xi, xi, 0x111, 0xF, 0xF, false)); xi = (int)x;
  x = min(x, (unsigned)__builtin_amdgcn_update_dpp(xi, xi, 0x112, 0xF, 0xF, false)); xi = (int)x;
  x = min(x, (unsigned)__builtin_amdgcn_update_dpp(xi, xi, 0x114, 0xF, 0xF, false)); xi = (int)x;
  x = min(x, (unsigned)__builtin_amdgcn_update_dpp(xi, xi, 0x118, 0xF, 0xF, false)); xi = (int)x;
  x = min(x, (unsigned)__builtin_amdgcn_update_dpp(xi, xi, 0x142, 0xA, 0xF, false)); xi = (int)x;
  x = min(x, (unsigned)__builtin_amdgcn_update_dpp(xi, xi, 0x143, 0xC, 0xF, false));
  return (unsigned)__builtin_amdgcn_readlane((int)x, 63);
}

// ------- fused QKV GEMM: split-fp16 MFMA (3-term Markidis), M128 x N64 ------
// v-tiles (n0 >= 1536) skip the lo-plane cross terms: v feeds only PV (no
// selection), single-fp16 precision was validated passing in the R0 config.
// Saves 2/3 of MFMAs + lo staging on 1/3 of blocks (block-uniform branch).
__global__ __launch_bounds__(256) void qkv_gemm_mfma(
    const float* __restrict__ X, const float* __restrict__ W,
    const float* __restrict__ bias,
    _Float16* __restrict__ qhp, _Float16* __restrict__ qlp,
    _Float16* __restrict__ khp, _Float16* __restrict__ klp,
    float* __restrict__ vb)
{
  constexpr int LDH = 40; // fp16 row stride: 80B, 16B-aligned, 2-way banks
  __shared__ _Float16 AhH[128*LDH];
  __shared__ _Float16 AhL[128*LDH];
  __shared__ _Float16 BhH[64*LDH];
  __shared__ _Float16 BhL[64*LDH];
  int t = threadIdx.x;
  int wv = t >> 6, lane = t & 63;
  int quad = lane >> 4, l16 = lane & 15;
  int mt = blockIdx.x & 63, nt = blockIdx.x >> 6;
  int m0 = mt*128, n0 = nt*64;
  const bool needLo = (n0 < 1536);     // q,k need fp32-class; v doesn't
  const float* Ap = X + (size_t)m0*768;
  const float* Bp = W + (size_t)n0*768;
  f32x4v acc1[2][4] = {};   // hi*hi
  f32x4v acc2[2][4] = {};   // 2048*(hi*lo + lo*hi)
  for (int k0 = 0; k0 < 768; k0 += 32) {
    float4 av[4]; float4 bv[2];
#pragma unroll
    for (int i = 0; i < 4; ++i) {
      int q = t + i*256;
      av[i] = *(const float4*)(Ap + (size_t)(q>>3)*768 + k0 + (q&7)*4);
    }
#pragma unroll
    for (int i = 0; i < 2; ++i) {
      int q = t + i*256;
      bv[i] = *(const float4*)(Bp + (size_t)(q>>3)*768 + k0 + (q&7)*4);
    }
    __syncthreads();
#pragma unroll
    for (int i = 0; i < 4; ++i) {
      int q = t + i*256;
      f16x4 h;
      h[0]=(_Float16)av[i].x; h[1]=(_Float16)av[i].y;
      h[2]=(_Float16)av[i].z; h[3]=(_Float16)av[i].w;
      *(f16x4*)(&AhH[(q>>3)*LDH + (q&7)*4]) = h;
      if (needLo) {
        f16x4 l;
        l[0]=(_Float16)((av[i].x-(float)h[0])*2048.0f);
        l[1]=(_Float16)((av[i].y-(float)h[1])*2048.0f);
        l[2]=(_Float16)((av[i].z-(float)h[2])*2048.0f);
        l[3]=(_Float16)((av[i].w-(float)h[3])*2048.0f);
        *(f16x4*)(&AhL[(q>>3)*LDH + (q&7)*4]) = l;
      }
    }
#pragma unroll
    for (int i = 0; i < 2; ++i) {
      int q = t + i*256;
      f16x4 h;
      h[0]=(_Float16)bv[i].x; h[1]=(_Float16)bv[i].y;
      h[2]=(_Float16)bv[i].z; h[3]=(_Float16)bv[i].w;
      *(f16x4*)(&BhH[(q>>3)*LDH + (q&7)*4]) = h;
      if (needLo) {
        f16x4 l;
        l[0]=(_Float16)((bv[i].x-(float)h[0])*2048.0f);
        l[1]=(_Float16)((bv[i].y-(float)h[1])*2048.0f);
        l[2]=(_Float16)((bv[i].z-(float)h[2])*2048.0f);
        l[3]=(_Float16)((bv[i].w-(float)h[3])*2048.0f);
        *(f16x4*)(&BhL[(q>>3)*LDH + (q&7)*4]) = l;
      }
    }
    __syncthreads();
    if (needLo) {
      f16x8 bfh[4], bfl[4];
#pragma unroll
      for (int ni = 0; ni < 4; ++ni) {
        bfh[ni] = *(f16x8*)(&BhH[(ni*16+l16)*LDH + quad*8]);
        bfl[ni] = *(f16x8*)(&BhL[(ni*16+l16)*LDH + quad*8]);
      }
#pragma unroll
      for (int mi = 0; mi < 2; ++mi) {
        f16x8 afh = *(f16x8*)(&AhH[(wv*32+mi*16+l16)*LDH + quad*8]);
        f16x8 afl = *(f16x8*)(&AhL[(wv*32+mi*16+l16)*LDH + quad*8]);
#pragma unroll
        for (int ni = 0; ni < 4; ++ni) {
          acc1[mi][ni] = __builtin_amdgcn_mfma_f32_16x16x32_f16(afh, bfh[ni], acc1[mi][ni], 0, 0, 0);
          acc2[mi][ni] = __builtin_amdgcn_mfma_f32_16x16x32_f16(afh, bfl[ni], acc2[mi][ni], 0, 0, 0);
          acc2[mi][ni] = __builtin_amdgcn_mfma_f32_16x16x32_f16(afl, bfh[ni], acc2[mi][ni], 0, 0, 0);
        }
      }
    } else {
      f16x8 bfh[4];
#pragma unroll
      for (int ni = 0; ni < 4; ++ni)
        bfh[ni] = *(f16x8*)(&BhH[(ni*16+l16)*LDH + quad*8]);
#pragma unroll
      for (int mi = 0; mi < 2; ++mi) {
        f16x8 afh = *(f16x8*)(&AhH[(wv*32+mi*16+l16)*LDH + quad*8]);
#pragma unroll
        for (int ni = 0; ni < 4; ++ni)
          acc1[mi][ni] = __builtin_amdgcn_mfma_f32_16x16x32_f16(afh, bfh[ni], acc1[mi][ni], 0, 0, 0);
      }
    }
  }
  int which = n0 / Cn;
  int rem0 = n0 - which*Cn;
  int h0 = rem0 >> 6;
  float sc = which == 0 ? 0.125f : 1.0f;
#pragma unroll
  for (int ni = 0; ni < 4; ++ni) {
    float bsv = bias[n0 + ni*16 + l16];
    int dd = (ni*16 + l16) & 63;
#pragma unroll
    for (int mi = 0; mi < 2; ++mi)
#pragma unroll
      for (int r = 0; r < 4; ++r) {
        int gm = m0 + wv*32 + mi*16 + quad*4 + r;
        int bbi = gm >> 10, nn = gm & 1023;
        size_t idx = (((size_t)(bbi*Hn + h0))*Nn + nn)*Dn + dd;
        float val = (acc1[mi][ni][r] + acc2[mi][ni][r] * (1.0f/2048.0f) + bsv) * sc;
        if (which == 2) {
          vb[idx] = val;
        } else {
          _Float16 hh = (_Float16)val;
          _Float16 ll = (_Float16)((val - (float)hh) * 2048.0f);
          if (which == 0) { qhp[idx] = hh; qlp[idx] = ll; }
          else            { khp[idx] = hh; klp[idx] = ll; }
        }
      }
  }
}

// ------- fp16 MFMA GEMM core (M128 x N64 tile, 4 waves, 16x16x32_f16) -------
template <typename Epi>
__device__ __forceinline__ void mfma_gemm_body(
    const float* __restrict__ Xp, const float* __restrict__ Wp, Epi epi)
{
  constexpr int LDH = 40;
  __shared__ _Float16 Ah[128*LDH];
  __shared__ _Float16 Bh[64*LDH];
  int t = threadIdx.x;
  int wv = t >> 6, lane = t & 63;
  int quad = lane >> 4, l16 = lane & 15;
  int mt = blockIdx.x & 63, nt = blockIdx.x >> 6;
  int m0 = mt*128, n0 = nt*64;
  f32x4v acc[2][4] = {};
  for (int k0 = 0; k0 < 768; k0 += 32) {
    float4 av[4]; float4 bv[2];
#pragma unroll
    for (int i = 0; i < 4; ++i) {
      int q = t + i*256;
      av[i] = *(const float4*)(Xp + (size_t)(m0+(q>>3))*768 + k0 + (q&7)*4);
    }
#pragma unroll
    for (int i = 0; i < 2; ++i) {
      int q = t + i*256;
      bv[i] = *(const float4*)(Wp + (size_t)(n0+(q>>3))*768 + k0 + (q&7)*4);
    }
    __syncthreads();
#pragma unroll
    for (int i = 0; i < 4; ++i) {
      int q = t + i*256;
      f16x4 h; h[0]=(_Float16)av[i].x; h[1]=(_Float16)av[i].y;
               h[2]=(_Float16)av[i].z; h[3]=(_Float16)av[i].w;
      *(f16x4*)(&Ah[(q>>3)*LDH + (q&7)*4]) = h;
    }
#pragma unroll
    for (int i = 0; i < 2; ++i) {
      int q = t + i*256;
      f16x4 h; h[0]=(_Float16)bv[i].x; h[1]=(_Float16)bv[i].y;
               h[2]=(_Float16)bv[i].z; h[3]=(_Float16)bv[i].w;
      *(f16x4*)(&Bh[(q>>3)*LDH + (q&7)*4]) = h;
    }
    __syncthreads();
    f16x8 bf[4], af;
#pragma unroll
    for (int ni = 0; ni < 4; ++ni)
      bf[ni] = *(f16x8*)(&Bh[(ni*16+l16)*LDH + quad*8]);
#pragma unroll
    for (int mi = 0; mi < 2; ++mi) {
      af = *(f16x8*)(&Ah[(wv*32+mi*16+l16)*LDH + quad*8]);
#pragma unroll
      for (int ni = 0; ni < 4; ++ni)
        acc[mi][ni] = __builtin_amdgcn_mfma_f32_16x16x32_f16(af, bf[ni], acc[mi][ni], 0, 0, 0);
    }
  }
#pragma unroll
  for (int mi = 0; mi < 2; ++mi)
#pragma unroll
    for (int ni = 0; ni < 4; ++ni)
#pragma unroll
      for (int r = 0; r < 4; ++r) {
        int gm = m0 + wv*32 + mi*16 + quad*4 + r;
        int gn = n0 + ni*16 + l16;
        epi(gm, gn, acc[mi][ni][r]);
      }
}

__global__ __launch_bounds__(256) void proj_mfma(
    const float* __restrict__ Xp, const float* __restrict__ Wp,
    const float* __restrict__ bias, float* __restrict__ Out)
{
  mfma_gemm_body(Xp, Wp, [=](int gm, int gn, float val) {
    Out[(size_t)gm*768 + gn] = val + bias[gn];
  });
}

// ---------------- Attention: exact R10 source (measured best 303us) ---------
// (512,8)/32-VGPR+spill @83% occ = 303us. R14 showed the spill source is the
// u0/u1 score arrays (radix re-reads), NOT the K fragments: single-buffering
// K left WRITE_SIZE unchanged and lost the prefetch (+10us). Keep prefetch.
__global__ __launch_bounds__(512, 8) void attn_kernel(
    const _Float16* __restrict__ qh, const _Float16* __restrict__ ql,
    const _Float16* __restrict__ kh, const _Float16* __restrict__ kl,
    const float* __restrict__ vB, const int* __restrict__ kptr,
    float* __restrict__ out)
{
  constexpr int G = 16, CAP = 128, CAPP = CAP + 4, LDB = 132;
  __shared__ float  Bx[2][G][LDB];     // 16896 B score-exchange chunks
  __shared__ float2 PairS[G][CAPP];    // 16896 B compacted (wgt, idx) lists

  int t = threadIdx.x;
  int bh = blockIdx.x >> 6;          // 0..95  (b*12+h)
  int qg = blockIdx.x & 63;
  int qbase = qg * G;
  int w = t >> 6, lane = t & 63;
  int quad = lane >> 4, l16 = lane & 15;

  const _Float16* QH = qh + (size_t)bh * Nn * Dn;
  const _Float16* QL = ql + (size_t)bh * Nn * Dn;
  const _Float16* KH = kh + (size_t)bh * Nn * Dn;
  const _Float16* KL = kl + (size_t)bh * Nn * Dn;
  const float*   Vbh = vB + (size_t)bh * Nn * Dn;

  int r0 = w*2, r1 = r0 + 1;
  unsigned u0[16], u1[16];

  // Q fragments (A operand), reused across all 8 k-tiles of this wave
  f16x8 aqh[2], aql[2];
  {
    size_t qoff = (size_t)(qbase + l16) * Dn + quad * 8;
#pragma unroll
    for (int c = 0; c < 2; ++c) {
      aqh[c] = *(const f16x8*)(QH + qoff + c*32);
      aql[c] = *(const f16x8*)(QL + qoff + c*32);
    }
  }
  // K fragments: depth-1 prefetch ping-pong; tile of round j = w + 8j
  f16x8 bhf[2][2], blf[2][2];
  {
    size_t koff = (size_t)(16*w + l16) * Dn + quad*8;
#pragma unroll
    for (int c = 0; c < 2; ++c) {
      bhf[0][c] = *(const f16x8*)(KH + koff + c*32);
      blf[0][c] = *(const f16x8*)(KL + koff + c*32);
    }
  }
#pragma unroll
  for (int j = 0; j < 8; ++j) {
    if (j < 7) {
      size_t koff = (size_t)(16*w + 128*(j+1) + l16) * Dn + quad*8;
#pragma unroll
      for (int c = 0; c < 2; ++c) {
        bhf[(j+1)&1][c] = *(const f16x8*)(KH + koff + c*32);
        blf[(j+1)&1][c] = *(const f16x8*)(KL + koff + c*32);
      }
    }
    int cb = j & 1;
    f32x4v a1 = {}, a2 = {};
    a1 = __builtin_amdgcn_mfma_f32_16x16x32_f16(aqh[0], bhf[cb][0], a1, 0,0,0);
    a1 = __builtin_amdgcn_mfma_f32_16x16x32_f16(aqh[1], bhf[cb][1], a1, 0,0,0);
    a2 = __builtin_amdgcn_mfma_f32_16x16x32_f16(aqh[0], blf[cb][0], a2, 0,0,0);
    a2 = __builtin_amdgcn_mfma_f32_16x16x32_f16(aqh[1], blf[cb][1], a2, 0,0,0);
    a2 = __builtin_amdgcn_mfma_f32_16x16x32_f16(aql[0], bhf[cb][0], a2, 0,0,0);
    a2 = __builtin_amdgcn_mfma_f32_16x16x32_f16(aql[1], bhf[cb][1], a2, 0,0,0);
    // write this round's 16-col slice: global col = 128j + (w*16 + l16)
#pragma unroll
    for (int r2 = 0; r2 < 4; ++r2)
      Bx[cb][quad*4 + r2][w*16 + l16] = a1[r2] + a2[r2] * (1.0f/2048.0f);
    __syncthreads();
    // read own 2 rows: u[2j] <- col lane+128j, u[2j+1] <- col lane+64+128j
    u0[2*j]   = toOrd(Bx[cb][r0][lane]);
    u0[2*j+1] = toOrd(Bx[cb][r0][lane + 64]);
    u1[2*j]   = toOrd(Bx[cb][r1][lane]);
    u1[2*j+1] = toOrd(Bx[cb][r1][lane + 64]);
  }

  int kval = *kptr;
  bool doSel = (kval > 0 && kval < Nn);

  unsigned mu0 = u0[0], mu1 = u1[0];
#pragma unroll
  for (int i = 1; i < 16; ++i) { mu0 = max(mu0, u0[i]); mu1 = max(mu1, u1[i]); }
  float m0 = invOrd(wave_max_u32(mu0));
  float m1 = invOrd(wave_max_u32(mu1));

  // ---- dual-row ballot-counted radix bisection for the k-th largest -------
  unsigned thr0 = 0u, thr1 = 0u;
  if (doSel) {
    unsigned res0 = 0u, res1 = 0u;
    bool done0 = false, done1 = false;
    for (int bit = 31; bit >= 0; --bit) {
      if (!done0) {
        unsigned cand = res0 | (1u << bit);
        int ct = 0;
#pragma unroll
        for (int i = 0; i < 16; ++i)
          ct += __popcll(__ballot(u0[i] >= cand));
        if (ct == kval) {
          unsigned mn = 0xFFFFFFFFu;
#pragma unroll
          for (int i = 0; i < 16; ++i)
            if (u0[i] >= cand && u0[i] < mn) mn = u0[i];
          res0 = wave_min_u32(mn);
          done0 = true;
        } else if (ct > kval) res0 = cand;
      }
      if (!done1) {
        unsigned cand = res1 | (1u << bit);
        int ct = 0;
#pragma unroll
        for (int i = 0; i < 16; ++i)
          ct += __popcll(__ballot(u1[i] >= cand));
        if (ct == kval) {
          unsigned mn = 0xFFFFFFFFu;
#pragma unroll
          for (int i = 0; i < 16; ++i)
            if (u1[i] >= cand && u1[i] < mn) mn = u1[i];
          res1 = wave_min_u32(mn);
          done1 = true;
        } else if (ct > kval) res1 = cand;
      }
      if (done0 && done1) break;
    }
    thr0 = res0; thr1 = res1;
  }

  // ---- dual-row exp + compaction into Pair lists --------------------------
  float2* Pair0 = &PairS[r0][0];
  float2* Pair1 = &PairS[r1][0];
  float Zl0 = 0.f, Zl1 = 0.f;
  int cnt0 = 0, cnt1 = 0;
#pragma unroll
  for (int i = 0; i < 16; ++i) {
    bool k0 = (u0[i] >= thr0);
    unsigned long long mk0 = __ballot(k0);
    if (k0) {
      float wgt = __expf(invOrd(u0[i]) - m0);
      Zl0 += wgt;
      int pos = cnt0 + lane_excl_cnt(mk0);
      if (pos < CAP) {
        float2 pr; pr.x = wgt; pr.y = __int_as_float(lane + 64*i);
        Pair0[pos] = pr;
      }
    }
    cnt0 += __popcll(mk0);
    bool k1 = (u1[i] >= thr1);
    unsigned long long mk1 = __ballot(k1);
    if (k1) {
      float wgt = __expf(invOrd(u1[i]) - m1);
      Zl1 += wgt;
      int pos = cnt1 + lane_excl_cnt(mk1);
      if (pos < CAP) {
        float2 pr; pr.x = wgt; pr.y = __int_as_float(lane + 64*i);
        Pair1[pos] = pr;
      }
    }
    cnt1 += __popcll(mk1);
  }
  float Z0 = wave_sum_f32(Zl0);
  float Z1 = wave_sum_f32(Zl1);

  // zero-pad 4 entries past each list so 4-wide PV needs no tail guards
  if (lane < 4) {
    float2 z; z.x = 0.f; z.y = __int_as_float(0);
    if (cnt0 <= CAP) Pair0[cnt0 + lane] = z;
    if (cnt1 <= CAP) Pair1[cnt1 + lane] = z;
  }

  // ---- PV ------------------------------------------------------------------
  float acc0 = 0.f, acc1 = 0.f;
  bool fast0 = (cnt0 <= CAP), fast1 = (cnt1 <= CAP);
  if (fast0 && fast1) {
    int nc = min(cnt0, cnt1);
    int i = 0;
    for (; i < nc; i += 4) {          // joint: 8 outstanding V-row loads
      float2 p00 = Pair0[i],   p01 = Pair0[i+1];
      float2 p02 = Pair0[i+2], p03 = Pair0[i+3];
      float2 p10 = Pair1[i],   p11 = Pair1[i+1];
      float2 p12 = Pair1[i+2], p13 = Pair1[i+3];
      float v00 = Vbh[(size_t)__float_as_int(p00.y)*Dn + lane];
      float v01 = Vbh[(size_t)__float_as_int(p01.y)*Dn + lane];
      float v02 = Vbh[(size_t)__float_as_int(p02.y)*Dn + lane];
      float v03 = Vbh[(size_t)__float_as_int(p03.y)*Dn + lane];
      float v10 = Vbh[(size_t)__float_as_int(p10.y)*Dn + lane];
      float v11 = Vbh[(size_t)__float_as_int(p11.y)*Dn + lane];
      float v12 = Vbh[(size_t)__float_as_int(p12.y)*Dn + lane];
      float v13 = Vbh[(size_t)__float_as_int(p13.y)*Dn + lane];
      acc0 = fmaf(p00.x, v00, acc0); acc0 = fmaf(p01.x, v01, acc0);
      acc0 = fmaf(p02.x, v02, acc0); acc0 = fmaf(p03.x, v03, acc0);
      acc1 = fmaf(p10.x, v10, acc1); acc1 = fmaf(p11.x, v11, acc1);
      acc1 = fmaf(p12.x, v12, acc1); acc1 = fmaf(p13.x, v13, acc1);
    }
    for (; i < cnt0; i += 4) {        // row0 tail
      float2 p0 = Pair0[i],   p1 = Pair0[i+1];
      float2 p2 = Pair0[i+2], p3 = Pair0[i+3];
      float v0 = Vbh[(size_t)__float_as_int(p0.y)*Dn + lane];
      float v1 = Vbh[(size_t)__float_as_int(p1.y)*Dn + lane];
      float v2 = Vbh[(size_t)__float_as_int(p2.y)*Dn + lane];
      float v3 = Vbh[(size_t)__float_as_int(p3.y)*Dn + lane];
      acc0 = fmaf(p0.x, v0, acc0); acc0 = fmaf(p1.x, v1, acc0);
      acc0 = fmaf(p2.x, v2, acc0); acc0 = fmaf(p3.x, v3, acc0);
    }
    for (; i < cnt1; i += 4) {        // row1 tail
      float2 p0 = Pair1[i],   p1 = Pair1[i+1];
      float2 p2 = Pair1[i+2], p3 = Pair1[i+3];
      float v0 = Vbh[(size_t)__float_as_int(p0.y)*Dn + lane];
      float v1 = Vbh[(size_t)__float_as_int(p1.y)*Dn + lane];
      float v2 = Vbh[(size_t)__float_as_int(p2.y)*Dn + lane];
      float v3 = Vbh[(size_t)__float_as_int(p3.y)*Dn + lane];
      acc1 = fmaf(p0.x, v0, acc1); acc1 = fmaf(p1.x, v1, acc1);
      acc1 = fmaf(p2.x, v2, acc1); acc1 = fmaf(p3.x, v3, acc1);
    }
  } else {
    // rare: oversize list (selection disabled or heavy ties). Weights are
    // re-derived from registers via shuffle; slow but tiny-LDS and correct.
    if (fast0) {
      for (int i = 0; i < cnt0; i += 4) {
        float2 p0 = Pair0[i],   p1 = Pair0[i+1];
        float2 p2 = Pair0[i+2], p3 = Pair0[i+3];
        float v0 = Vbh[(size_t)__float_as_int(p0.y)*Dn + lane];
        float v1 = Vbh[(size_t)__float_as_int(p1.y)*Dn + lane];
        float v2 = Vbh[(size_t)__float_as_int(p2.y)*Dn + lane];
        float v3 = Vbh[(size_t)__float_as_int(p3.y)*Dn + lane];
        acc0 = fmaf(p0.x, v0, acc0); acc0 = fmaf(p1.x, v1, acc0);
        acc0 = fmaf(p2.x, v2, acc0); acc0 = fmaf(p3.x, v3, acc0);
      }
    } else {
#pragma unroll
      for (int i = 0; i < 16; ++i) {
        float wbase = (u0[i] >= thr0) ? __expf(invOrd(u0[i]) - m0) : 0.f;
        for (int src = 0; src < 64; ++src) {
          float wgt = __shfl(wbase, src);
          if (wgt != 0.f)
            acc0 = fmaf(wgt, Vbh[(size_t)(src + 64*i)*Dn + lane], acc0);
        }
      }
    }
    if (fast1) {
      for (int i = 0; i < cnt1; i += 4) {
        float2 p0 = Pair1[i],   p1 = Pair1[i+1];
        float2 p2 = Pair1[i+2], p3 = Pair1[i+3];
        float v0 = Vbh[(size_t)__float_as_int(p0.y)*Dn + lane];
        float v1 = Vbh[(size_t)__float_as_int(p1.y)*Dn + lane];
        float v2 = Vbh[(size_t)__float_as_int(p2.y)*Dn + lane];
        float v3 = Vbh[(size_t)__float_as_int(p3.y)*Dn + lane];
        acc1 = fmaf(p0.x, v0, acc1); acc1 = fmaf(p1.x, v1, acc1);
        acc1 = fmaf(p2.x, v2, acc1); acc1 = fmaf(p3.x, v3, acc1);
      }
    } else {
#pragma unroll
      for (int i = 0; i < 16; ++i) {
        float wbase = (u1[i] >= thr1) ? __expf(invOrd(u1[i]) - m1) : 0.f;
        for (int src = 0; src < 64; ++src) {
          float wgt = __shfl(wbase, src);
          if (wgt != 0.f)
            acc1 = fmaf(wgt, Vbh[(size_t)(src + 64*i)*Dn + lane], acc1);
        }
      }
    }
  }

  int b = bh / Hn, h = bh - b*Hn;
  out[((size_t)(b*Nn + qbase + r0))*Cn + h*Dn + lane] = acc0 * (1.0f / Z0);
  out[((size_t)(b*Nn + qbase + r1))*Cn + h*Dn + lane] = acc1 * (1.0f / Z1);
}

extern "C" void kernel_launch(void* const* d_in, const int* in_sizes, int n_in,
                              void* d_out, int out_size, void* d_ws, size_t ws_size,
                              hipStream_t stream) {
  const float* x      = (const float*)d_in[0];
  const float* qkv_w  = (const float*)d_in[1];
  const float* qkv_b  = (const float*)d_in[2];
  const float* proj_w = (const float*)d_in[3];
  const float* proj_b = (const float*)d_in[4];
  const int*   kptr   = (const int*)d_in[5];

  const size_t sz = (size_t)Bn * Hn * Nn * Dn;   // 6291456 elements
  _Float16* qh = (_Float16*)d_ws;                // split-fp16 planes
  _Float16* ql = qh + sz;
  _Float16* kh = ql + sz;
  _Float16* kl = kh + sz;
  float* vbuf  = (float*)(kl + sz);
  float* att   = vbuf + sz;                      // (B,N,C)
  float* outp  = (float*)d_out;

  qkv_gemm_mfma<<<dim3(36*64), 256, 0, stream>>>(x, qkv_w, qkv_b,
                                                 qh, ql, kh, kl, vbuf);
  attn_kernel<<<dim3(Bn*Hn*(Nn/16)), 512, 0, stream>>>(qh, ql, kh, kl,
                                                       vbuf, kptr, att);
  proj_mfma<<<dim3(12*64), 256, 0, stream>>>(att, proj_w, proj_b, outp);
}

// Round 18
// 512.297 us; speedup vs baseline: 1.1553x; 1.0140x over previous
//
#include <hip/hip_runtime.h>

constexpr int Bn = 8, Nn = 1024, Cn = 768, Hn = 12, Dn = 64;

typedef _Float16 f16x4 __attribute__((ext_vector_type(4)));
typedef _Float16 f16x8 __attribute__((ext_vector_type(8)));
typedef float    f32x4v __attribute__((ext_vector_type(4)));

__device__ __forceinline__ unsigned toOrd(float f) {
  unsigned u = __float_as_uint(f);
  return (u & 0x80000000u) ? ~u : (u | 0x80000000u);
}
__device__ __forceinline__ float invOrd(unsigned v) {
  unsigned b = (v & 0x80000000u) ? (v & 0x7FFFFFFFu) : ~v;
  return __uint_as_float(b);
}
// popcount of mask bits strictly below this lane (v_mbcnt pair)
__device__ __forceinline__ int lane_excl_cnt(unsigned long long m) {
  return __builtin_amdgcn_mbcnt_hi((unsigned)(m >> 32),
         __builtin_amdgcn_mbcnt_lo((unsigned)m, 0));
}

// ---- wave64 reductions via DPP ---------------------------------------------
__device__ __forceinline__ float wave_sum_f32(float x) {
  int xi = __float_as_int(x);
  x += __int_as_float(__builtin_amdgcn_update_dpp(0, xi, 0x111, 0xF, 0xF, false)); xi = __float_as_int(x);
  x += __int_as_float(__builtin_amdgcn_update_dpp(0, xi, 0x112, 0xF, 0xF, false)); xi = __float_as_int(x);
  x += __int_as_float(__builtin_amdgcn_update_dpp(0, xi, 0x114, 0xF, 0xF, false)); xi = __float_as_int(x);
  x += __int_as_float(__builtin_amdgcn_update_dpp(0, xi, 0x118, 0xF, 0xF, false)); xi = __float_as_int(x);
  x += __int_as_float(__builtin_amdgcn_update_dpp(0, xi, 0x142, 0xA, 0xF, false)); xi = __float_as_int(x);
  x += __int_as_float(__builtin_amdgcn_update_dpp(0, xi, 0x143, 0xC, 0xF, false));
  return __int_as_float(__builtin_amdgcn_readlane(__float_as_int(x), 63));
}
__device__ __forceinline__ unsigned wave_max_u32(unsigned x) {
  int xi = (int)x;
  x = max(x, (unsigned)__builtin_amdgcn_update_dpp(xi, xi, 0x111, 0xF, 0xF, false)); xi = (int)x;
  x = max(x, (unsigned)__builtin_amdgcn_update_dpp(xi, xi, 0x112, 0xF, 0xF, false)); xi = (int)x;
  x = max(x, (unsigned)__builtin_amdgcn_update_dpp(xi, xi, 0x114, 0xF, 0xF, false)); xi = (int)x;
  x = max(x, (unsigned)__builtin_amdgcn_update_dpp(xi, xi, 0x118, 0xF, 0xF, false)); xi = (int)x;
  x = max(x, (unsigned)__builtin_amdgcn_update_dpp(xi, xi, 0x142, 0xA, 0xF, false)); xi = (int)x;
  x = max(x, (unsigned)__builtin_amdgcn_update_dpp(xi, xi, 0x143, 0xC, 0xF, false));
  return (unsigned)__builtin_amdgcn_readlane((int)x, 63);
}
__device__ __forceinline__ unsigned wave_min_u32(unsigned x) {
  int xi = (int)x;
  x = min(x, (unsigned)__builtin_amdgcn_update_dpp(xi, xi, 0x111, 0xF, 0xF, false)); xi = (int)x;
  x = min(x, (unsigned)__builtin_amdgcn_update_dpp(xi, xi, 0x112, 0xF, 0xF, false)); xi = (int)x;
  x = min(x, (unsigned)__builtin_amdgcn_update_dpp(xi, xi, 0x114, 0xF, 0xF, false)); xi = (int)x;
  x = min(x, (unsigned)__builtin_amdgcn_update_dpp(xi, xi, 0x118, 0xF, 0xF, false)); xi = (int)x;
  x = min(x, (unsigned)__builtin_amdgcn_update_dpp(xi, xi, 0x142, 0xA, 0xF, false)); xi = (int)x;
  x = min(x, (unsigned)__builtin_amdgcn_update_dpp(xi, xi, 0x143, 0xC, 0xF, false));
  return (unsigned)__builtin_amdgcn_readlane((int)x, 63);
}

// ------- one-shot split of X and W into fp16 hi/lo planes -------------------
// Removes the 36x/64x redundant per-block conversion from the QKV GEMM.
// Values identical to the old in-loop split4 -> MFMA inputs bit-identical.
__global__ __launch_bounds__(256) void split_planes(
    const float* __restrict__ X, const float* __restrict__ W,
    _Float16* __restrict__ xh, _Float16* __restrict__ xl,
    _Float16* __restrict__ wh, _Float16* __restrict__ wl)
{
  const int X4 = (8192*768)/4;        // 1572864 float4s of X
  const int T4 = X4 + (2304*768)/4;   // + 442368 float4s of W
  for (int idx = blockIdx.x*256 + threadIdx.x; idx < T4;
       idx += gridDim.x*256) {
    float4 v = (idx < X4) ? ((const float4*)X)[idx]
                          : ((const float4*)W)[idx - X4];
    f16x4 h, l;
    h[0]=(_Float16)v.x; h[1]=(_Float16)v.y; h[2]=(_Float16)v.z; h[3]=(_Float16)v.w;
    l[0]=(_Float16)((v.x-(float)h[0])*2048.0f);
    l[1]=(_Float16)((v.y-(float)h[1])*2048.0f);
    l[2]=(_Float16)((v.z-(float)h[2])*2048.0f);
    l[3]=(_Float16)((v.w-(float)h[3])*2048.0f);
    if (idx < X4) {
      *(f16x4*)(xh + (size_t)idx*4) = h;
      *(f16x4*)(xl + (size_t)idx*4) = l;
    } else {
      size_t j = (size_t)(idx - X4)*4;
      *(f16x4*)(wh + j) = h;
      *(f16x4*)(wl + j) = l;
    }
  }
}

// ------- fused QKV GEMM: pre-split fp16 MFMA, M128 x N64 --------------------
// Inputs already split (hi + lo*2048). Staging is pure f16x8 copy - zero
// conversion VALU. v-tiles (n0 >= 1536) skip lo loads/MFMAs entirely
// (single-fp16 v validated passing in R0 config).
__global__ __launch_bounds__(256) void qkv_gemm_mfma(
    const _Float16* __restrict__ Xh, const _Float16* __restrict__ Xl,
    const _Float16* __restrict__ Wh, const _Float16* __restrict__ Wl,
    const float* __restrict__ bias,
    _Float16* __restrict__ qhp, _Float16* __restrict__ qlp,
    _Float16* __restrict__ khp, _Float16* __restrict__ klp,
    float* __restrict__ vb)
{
  constexpr int LDH = 40; // fp16 row stride: 80B, 16B-aligned, 2-way banks
  __shared__ _Float16 AhH[128*LDH];
  __shared__ _Float16 AhL[128*LDH];
  __shared__ _Float16 BhH[64*LDH];
  __shared__ _Float16 BhL[64*LDH];
  int t = threadIdx.x;
  int wv = t >> 6, lane = t & 63;
  int quad = lane >> 4, l16 = lane & 15;
  int mt = blockIdx.x & 63, nt = blockIdx.x >> 6;
  int m0 = mt*128, n0 = nt*64;
  const bool needLo = (n0 < 1536);     // q,k need fp32-class; v doesn't
  f32x4v acc1[2][4] = {};   // hi*hi
  f32x4v acc2[2][4] = {};   // 2048*(hi*lo + lo*hi)
  for (int k0 = 0; k0 < 768; k0 += 32) {
    // A tile: 128 rows x 32 k = 512 f16x8 chunks; 2/thread. row=q>>2, ko=(q&3)*8
    f16x8 a_h[2], a_l[2], b_h, b_l;
#pragma unroll
    for (int i = 0; i < 2; ++i) {
      int q = t + i*256;
      size_t off = (size_t)(m0 + (q>>2))*768 + k0 + (q&3)*8;
      a_h[i] = *(const f16x8*)(Xh + off);
      if (needLo) a_l[i] = *(const f16x8*)(Xl + off);
    }
    {   // B tile: 64 rows x 32 k = 256 chunks; 1/thread
      size_t off = (size_t)(n0 + (t>>2))*768 + k0 + (t&3)*8;
      b_h = *(const f16x8*)(Wh + off);
      if (needLo) b_l = *(const f16x8*)(Wl + off);
    }
    __syncthreads();
#pragma unroll
    for (int i = 0; i < 2; ++i) {
      int q = t + i*256;
      *(f16x8*)(&AhH[(q>>2)*LDH + (q&3)*8]) = a_h[i];
      if (needLo) *(f16x8*)(&AhL[(q>>2)*LDH + (q&3)*8]) = a_l[i];
    }
    *(f16x8*)(&BhH[(t>>2)*LDH + (t&3)*8]) = b_h;
    if (needLo) *(f16x8*)(&BhL[(t>>2)*LDH + (t&3)*8]) = b_l;
    __syncthreads();
    if (needLo) {
      f16x8 bfh[4], bfl[4];
#pragma unroll
      for (int ni = 0; ni < 4; ++ni) {
        bfh[ni] = *(f16x8*)(&BhH[(ni*16+l16)*LDH + quad*8]);
        bfl[ni] = *(f16x8*)(&BhL[(ni*16+l16)*LDH + quad*8]);
      }
#pragma unroll
      for (int mi = 0; mi < 2; ++mi) {
        f16x8 afh = *(f16x8*)(&AhH[(wv*32+mi*16+l16)*LDH + quad*8]);
        f16x8 afl = *(f16x8*)(&AhL[(wv*32+mi*16+l16)*LDH + quad*8]);
#pragma unroll
        for (int ni = 0; ni < 4; ++ni) {
          acc1[mi][ni] = __builtin_amdgcn_mfma_f32_16x16x32_f16(afh, bfh[ni], acc1[mi][ni], 0, 0, 0);
          acc2[mi][ni] = __builtin_amdgcn_mfma_f32_16x16x32_f16(afh, bfl[ni], acc2[mi][ni], 0, 0, 0);
          acc2[mi][ni] = __builtin_amdgcn_mfma_f32_16x16x32_f16(afl, bfh[ni], acc2[mi][ni], 0, 0, 0);
        }
      }
    } else {
      f16x8 bfh[4];
#pragma unroll
      for (int ni = 0; ni < 4; ++ni)
        bfh[ni] = *(f16x8*)(&BhH[(ni*16+l16)*LDH + quad*8]);
#pragma unroll
      for (int mi = 0; mi < 2; ++mi) {
        f16x8 afh = *(f16x8*)(&AhH[(wv*32+mi*16+l16)*LDH + quad*8]);
#pragma unroll
        for (int ni = 0; ni < 4; ++ni)
          acc1[mi][ni] = __builtin_amdgcn_mfma_f32_16x16x32_f16(afh, bfh[ni], acc1[mi][ni], 0, 0, 0);
      }
    }
  }
  int which = n0 / Cn;
  int rem0 = n0 - which*Cn;
  int h0 = rem0 >> 6;
  float sc = which == 0 ? 0.125f : 1.0f;
#pragma unroll
  for (int ni = 0; ni < 4; ++ni) {
    float bsv = bias[n0 + ni*16 + l16];
    int dd = (ni*16 + l16) & 63;
#pragma unroll
    for (int mi = 0; mi < 2; ++mi)
#pragma unroll
      for (int r = 0; r < 4; ++r) {
        int gm = m0 + wv*32 + mi*16 + quad*4 + r;
        int bbi = gm >> 10, nn = gm & 1023;
        size_t idx = (((size_t)(bbi*Hn + h0))*Nn + nn)*Dn + dd;
        float val = (acc1[mi][ni][r] + acc2[mi][ni][r] * (1.0f/2048.0f) + bsv) * sc;
        if (which == 2) {
          vb[idx] = val;
        } else {
          _Float16 hh = (_Float16)val;
          _Float16 ll = (_Float16)((val - (float)hh) * 2048.0f);
          if (which == 0) { qhp[idx] = hh; qlp[idx] = ll; }
          else            { khp[idx] = hh; klp[idx] = ll; }
        }
      }
  }
}

// ------- fp16 MFMA GEMM core (M128 x N64 tile, 4 waves, 16x16x32_f16) -------
template <typename Epi>
__device__ __forceinline__ void mfma_gemm_body(
    const float* __restrict__ Xp, const float* __restrict__ Wp, Epi epi)
{
  constexpr int LDH = 40;
  __shared__ _Float16 Ah[128*LDH];
  __shared__ _Float16 Bh[64*LDH];
  int t = threadIdx.x;
  int wv = t >> 6, lane = t & 63;
  int quad = lane >> 4, l16 = lane & 15;
  int mt = blockIdx.x & 63, nt = blockIdx.x >> 6;
  int m0 = mt*128, n0 = nt*64;
  f32x4v acc[2][4] = {};
  for (int k0 = 0; k0 < 768; k0 += 32) {
    float4 av[4]; float4 bv[2];
#pragma unroll
    for (int i = 0; i < 4; ++i) {
      int q = t + i*256;
      av[i] = *(const float4*)(Xp + (size_t)(m0+(q>>3))*768 + k0 + (q&7)*4);
    }
#pragma unroll
    for (int i = 0; i < 2; ++i) {
      int q = t + i*256;
      bv[i] = *(const float4*)(Wp + (size_t)(n0+(q>>3))*768 + k0 + (q&7)*4);
    }
    __syncthreads();
#pragma unroll
    for (int i = 0; i < 4; ++i) {
      int q = t + i*256;
      f16x4 h; h[0]=(_Float16)av[i].x; h[1]=(_Float16)av[i].y;
               h[2]=(_Float16)av[i].z; h[3]=(_Float16)av[i].w;
      *(f16x4*)(&Ah[(q>>3)*LDH + (q&7)*4]) = h;
    }
#pragma unroll
    for (int i = 0; i < 2; ++i) {
      int q = t + i*256;
      f16x4 h; h[0]=(_Float16)bv[i].x; h[1]=(_Float16)bv[i].y;
               h[2]=(_Float16)bv[i].z; h[3]=(_Float16)bv[i].w;
      *(f16x4*)(&Bh[(q>>3)*LDH + (q&7)*4]) = h;
    }
    __syncthreads();
    f16x8 bf[4], af;
#pragma unroll
    for (int ni = 0; ni < 4; ++ni)
      bf[ni] = *(f16x8*)(&Bh[(ni*16+l16)*LDH + quad*8]);
#pragma unroll
    for (int mi = 0; mi < 2; ++mi) {
      af = *(f16x8*)(&Ah[(wv*32+mi*16+l16)*LDH + quad*8]);
#pragma unroll
      for (int ni = 0; ni < 4; ++ni)
        acc[mi][ni] = __builtin_amdgcn_mfma_f32_16x16x32_f16(af, bf[ni], acc[mi][ni], 0, 0, 0);
    }
  }
#pragma unroll
  for (int mi = 0; mi < 2; ++mi)
#pragma unroll
    for (int ni = 0; ni < 4; ++ni)
#pragma unroll
      for (int r = 0; r < 4; ++r) {
        int gm = m0 + wv*32 + mi*16 + quad*4 + r;
        int gn = n0 + ni*16 + l16;
        epi(gm, gn, acc[mi][ni][r]);
      }
}

__global__ __launch_bounds__(256) void proj_mfma(
    const float* __restrict__ Xp, const float* __restrict__ Wp,
    const float* __restrict__ bias, float* __restrict__ Out)
{
  mfma_gemm_body(Xp, Wp, [=](int gm, int gn, float val) {
    Out[(size_t)gm*768 + gn] = val + bias[gn];
  });
}

// ---------------- Attention: exact R10 source (measured best 303us) ---------
// (512,8)/32-VGPR+spill @83% occ = 303us. R14 showed the spill source is the
// u0/u1 score arrays (radix re-reads), NOT the K fragments: single-buffering
// K left WRITE_SIZE unchanged and lost the prefetch (+10us). Keep prefetch.
__global__ __launch_bounds__(512, 8) void attn_kernel(
    const _Float16* __restrict__ qh, const _Float16* __restrict__ ql,
    const _Float16* __restrict__ kh, const _Float16* __restrict__ kl,
    const float* __restrict__ vB, const int* __restrict__ kptr,
    float* __restrict__ out)
{
  constexpr int G = 16, CAP = 128, CAPP = CAP + 4, LDB = 132;
  __shared__ float  Bx[2][G][LDB];     // 16896 B score-exchange chunks
  __shared__ float2 PairS[G][CAPP];    // 16896 B compacted (wgt, idx) lists

  int t = threadIdx.x;
  int bh = blockIdx.x >> 6;          // 0..95  (b*12+h)
  int qg = blockIdx.x & 63;
  int qbase = qg * G;
  int w = t >> 6, lane = t & 63;
  int quad = lane >> 4, l16 = lane & 15;

  const _Float16* QH = qh + (size_t)bh * Nn * Dn;
  const _Float16* QL = ql + (size_t)bh * Nn * Dn;
  const _Float16* KH = kh + (size_t)bh * Nn * Dn;
  const _Float16* KL = kl + (size_t)bh * Nn * Dn;
  const float*   Vbh = vB + (size_t)bh * Nn * Dn;

  int r0 = w*2, r1 = r0 + 1;
  unsigned u0[16], u1[16];

  // Q fragments (A operand), reused across all 8 k-tiles of this wave
  f16x8 aqh[2], aql[2];
  {
    size_t qoff = (size_t)(qbase + l16) * Dn + quad * 8;
#pragma unroll
    for (int c = 0; c < 2; ++c) {
      aqh[c] = *(const f16x8*)(QH + qoff + c*32);
      aql[c] = *(const f16x8*)(QL + qoff + c*32);
    }
  }
  // K fragments: depth-1 prefetch ping-pong; tile of round j = w + 8j
  f16x8 bhf[2][2], blf[2][2];
  {
    size_t koff = (size_t)(16*w + l16) * Dn + quad*8;
#pragma unroll
    for (int c = 0; c < 2; ++c) {
      bhf[0][c] = *(const f16x8*)(KH + koff + c*32);
      blf[0][c] = *(const f16x8*)(KL + koff + c*32);
    }
  }
#pragma unroll
  for (int j = 0; j < 8; ++j) {
    if (j < 7) {
      size_t koff = (size_t)(16*w + 128*(j+1) + l16) * Dn + quad*8;
#pragma unroll
      for (int c = 0; c < 2; ++c) {
        bhf[(j+1)&1][c] = *(const f16x8*)(KH + koff + c*32);
        blf[(j+1)&1][c] = *(const f16x8*)(KL + koff + c*32);
      }
    }
    int cb = j & 1;
    f32x4v a1 = {}, a2 = {};
    a1 = __builtin_amdgcn_mfma_f32_16x16x32_f16(aqh[0], bhf[cb][0], a1, 0,0,0);
    a1 = __builtin_amdgcn_mfma_f32_16x16x32_f16(aqh[1], bhf[cb][1], a1, 0,0,0);
    a2 = __builtin_amdgcn_mfma_f32_16x16x32_f16(aqh[0], blf[cb][0], a2, 0,0,0);
    a2 = __builtin_amdgcn_mfma_f32_16x16x32_f16(aqh[1], blf[cb][1], a2, 0,0,0);
    a2 = __builtin_amdgcn_mfma_f32_16x16x32_f16(aql[0], bhf[cb][0], a2, 0,0,0);
    a2 = __builtin_amdgcn_mfma_f32_16x16x32_f16(aql[1], bhf[cb][1], a2, 0,0,0);
    // write this round's 16-col slice: global col = 128j + (w*16 + l16)
#pragma unroll
    for (int r2 = 0; r2 < 4; ++r2)
      Bx[cb][quad*4 + r2][w*16 + l16] = a1[r2] + a2[r2] * (1.0f/2048.0f);
    __syncthreads();
    // read own 2 rows: u[2j] <- col lane+128j, u[2j+1] <- col lane+64+128j
    u0[2*j]   = toOrd(Bx[cb][r0][lane]);
    u0[2*j+1] = toOrd(Bx[cb][r0][lane + 64]);
    u1[2*j]   = toOrd(Bx[cb][r1][lane]);
    u1[2*j+1] = toOrd(Bx[cb][r1][lane + 64]);
  }

  int kval = *kptr;
  bool doSel = (kval > 0 && kval < Nn);

  unsigned mu0 = u0[0], mu1 = u1[0];
#pragma unroll
  for (int i = 1; i < 16; ++i) { mu0 = max(mu0, u0[i]); mu1 = max(mu1, u1[i]); }
  float m0 = invOrd(wave_max_u32(mu0));
  float m1 = invOrd(wave_max_u32(mu1));

  // ---- dual-row ballot-counted radix bisection for the k-th largest -------
  unsigned thr0 = 0u, thr1 = 0u;
  if (doSel) {
    unsigned res0 = 0u, res1 = 0u;
    bool done0 = false, done1 = false;
    for (int bit = 31; bit >= 0; --bit) {
      if (!done0) {
        unsigned cand = res0 | (1u << bit);
        int ct = 0;
#pragma unroll
        for (int i = 0; i < 16; ++i)
          ct += __popcll(__ballot(u0[i] >= cand));
        if (ct == kval) {
          unsigned mn = 0xFFFFFFFFu;
#pragma unroll
          for (int i = 0; i < 16; ++i)
            if (u0[i] >= cand && u0[i] < mn) mn = u0[i];
          res0 = wave_min_u32(mn);
          done0 = true;
        } else if (ct > kval) res0 = cand;
      }
      if (!done1) {
        unsigned cand = res1 | (1u << bit);
        int ct = 0;
#pragma unroll
        for (int i = 0; i < 16; ++i)
          ct += __popcll(__ballot(u1[i] >= cand));
        if (ct == kval) {
          unsigned mn = 0xFFFFFFFFu;
#pragma unroll
          for (int i = 0; i < 16; ++i)
            if (u1[i] >= cand && u1[i] < mn) mn = u1[i];
          res1 = wave_min_u32(mn);
          done1 = true;
        } else if (ct > kval) res1 = cand;
      }
      if (done0 && done1) break;
    }
    thr0 = res0; thr1 = res1;
  }

  // ---- dual-row exp + compaction into Pair lists --------------------------
  float2* Pair0 = &PairS[r0][0];
  float2* Pair1 = &PairS[r1][0];
  float Zl0 = 0.f, Zl1 = 0.f;
  int cnt0 = 0, cnt1 = 0;
#pragma unroll
  for (int i = 0; i < 16; ++i) {
    bool k0 = (u0[i] >= thr0);
    unsigned long long mk0 = __ballot(k0);
    if (k0) {
      float wgt = __expf(invOrd(u0[i]) - m0);
      Zl0 += wgt;
      int pos = cnt0 + lane_excl_cnt(mk0);
      if (pos < CAP) {
        float2 pr; pr.x = wgt; pr.y = __int_as_float(lane + 64*i);
        Pair0[pos] = pr;
      }
    }
    cnt0 += __popcll(mk0);
    bool k1 = (u1[i] >= thr1);
    unsigned long long mk1 = __ballot(k1);
    if (k1) {
      float wgt = __expf(invOrd(u1[i]) - m1);
      Zl1 += wgt;
      int pos = cnt1 + lane_excl_cnt(mk1);
      if (pos < CAP) {
        float2 pr; pr.x = wgt; pr.y = __int_as_float(lane + 64*i);
        Pair1[pos] = pr;
      }
    }
    cnt1 += __popcll(mk1);
  }
  float Z0 = wave_sum_f32(Zl0);
  float Z1 = wave_sum_f32(Zl1);

  // zero-pad 4 entries past each list so 4-wide PV needs no tail guards
  if (lane < 4) {
    float2 z; z.x = 0.f; z.y = __int_as_float(0);
    if (cnt0 <= CAP) Pair0[cnt0 + lane] = z;
    if (cnt1 <= CAP) Pair1[cnt1 + lane] = z;
  }

  // ---- PV ------------------------------------------------------------------
  float acc0 = 0.f, acc1 = 0.f;
  bool fast0 = (cnt0 <= CAP), fast1 = (cnt1 <= CAP);
  if (fast0 && fast1) {
    int nc = min(cnt0, cnt1);
    int i = 0;
    for (; i < nc; i += 4) {          // joint: 8 outstanding V-row loads
      float2 p00 = Pair0[i],   p01 = Pair0[i+1];
      float2 p02 = Pair0[i+2], p03 = Pair0[i+3];
      float2 p10 = Pair1[i],   p11 = Pair1[i+1];
      float2 p12 = Pair1[i+2], p13 = Pair1[i+3];
      float v00 = Vbh[(size_t)__float_as_int(p00.y)*Dn + lane];
      float v01 = Vbh[(size_t)__float_as_int(p01.y)*Dn + lane];
      float v02 = Vbh[(size_t)__float_as_int(p02.y)*Dn + lane];
      float v03 = Vbh[(size_t)__float_as_int(p03.y)*Dn + lane];
      float v10 = Vbh[(size_t)__float_as_int(p10.y)*Dn + lane];
      float v11 = Vbh[(size_t)__float_as_int(p11.y)*Dn + lane];
      float v12 = Vbh[(size_t)__float_as_int(p12.y)*Dn + lane];
      float v13 = Vbh[(size_t)__float_as_int(p13.y)*Dn + lane];
      acc0 = fmaf(p00.x, v00, acc0); acc0 = fmaf(p01.x, v01, acc0);
      acc0 = fmaf(p02.x, v02, acc0); acc0 = fmaf(p03.x, v03, acc0);
      acc1 = fmaf(p10.x, v10, acc1); acc1 = fmaf(p11.x, v11, acc1);
      acc1 = fmaf(p12.x, v12, acc1); acc1 = fmaf(p13.x, v13, acc1);
    }
    for (; i < cnt0; i += 4) {        // row0 tail
      float2 p0 = Pair0[i],   p1 = Pair0[i+1];
      float2 p2 = Pair0[i+2], p3 = Pair0[i+3];
      float v0 = Vbh[(size_t)__float_as_int(p0.y)*Dn + lane];
      float v1 = Vbh[(size_t)__float_as_int(p1.y)*Dn + lane];
      float v2 = Vbh[(size_t)__float_as_int(p2.y)*Dn + lane];
      float v3 = Vbh[(size_t)__float_as_int(p3.y)*Dn + lane];
      acc0 = fmaf(p0.x, v0, acc0); acc0 = fmaf(p1.x, v1, acc0);
      acc0 = fmaf(p2.x, v2, acc0); acc0 = fmaf(p3.x, v3, acc0);
    }
    for (; i < cnt1; i += 4) {        // row1 tail
      float2 p0 = Pair1[i],   p1 = Pair1[i+1];
      float2 p2 = Pair1[i+2], p3 = Pair1[i+3];
      float v0 = Vbh[(size_t)__float_as_int(p0.y)*Dn + lane];
      float v1 = Vbh[(size_t)__float_as_int(p1.y)*Dn + lane];
      float v2 = Vbh[(size_t)__float_as_int(p2.y)*Dn + lane];
      float v3 = Vbh[(size_t)__float_as_int(p3.y)*Dn + lane];
      acc1 = fmaf(p0.x, v0, acc1); acc1 = fmaf(p1.x, v1, acc1);
      acc1 = fmaf(p2.x, v2, acc1); acc1 = fmaf(p3.x, v3, acc1);
    }
  } else {
    // rare: oversize list (selection disabled or heavy ties). Weights are
    // re-derived from registers via shuffle; slow but tiny-LDS and correct.
    if (fast0) {
      for (int i = 0; i < cnt0; i += 4) {
        float2 p0 = Pair0[i],   p1 = Pair0[i+1];
        float2 p2 = Pair0[i+2], p3 = Pair0[i+3];
        float v0 = Vbh[(size_t)__float_as_int(p0.y)*Dn + lane];
        float v1 = Vbh[(size_t)__float_as_int(p1.y)*Dn + lane];
        float v2 = Vbh[(size_t)__float_as_int(p2.y)*Dn + lane];
        float v3 = Vbh[(size_t)__float_as_int(p3.y)*Dn + lane];
        acc0 = fmaf(p0.x, v0, acc0); acc0 = fmaf(p1.x, v1, acc0);
        acc0 = fmaf(p2.x, v2, acc0); acc0 = fmaf(p3.x, v3, acc0);
      }
    } else {
#pragma unroll
      for (int i = 0; i < 16; ++i) {
        float wbase = (u0[i] >= thr0) ? __expf(invOrd(u0[i]) - m0) : 0.f;
        for (int src = 0; src < 64; ++src) {
          float wgt = __shfl(wbase, src);
          if (wgt != 0.f)
            acc0 = fmaf(wgt, Vbh[(size_t)(src + 64*i)*Dn + lane], acc0);
        }
      }
    }
    if (fast1) {
      for (int i = 0; i < cnt1; i += 4) {
        float2 p0 = Pair1[i],   p1 = Pair1[i+1];
        float2 p2 = Pair1[i+2], p3 = Pair1[i+3];
        float v0 = Vbh[(size_t)__float_as_int(p0.y)*Dn + lane];
        float v1 = Vbh[(size_t)__float_as_int(p1.y)*Dn + lane];
        float v2 = Vbh[(size_t)__float_as_int(p2.y)*Dn + lane];
        float v3 = Vbh[(size_t)__float_as_int(p3.y)*Dn + lane];
        acc1 = fmaf(p0.x, v0, acc1); acc1 = fmaf(p1.x, v1, acc1);
        acc1 = fmaf(p2.x, v2, acc1); acc1 = fmaf(p3.x, v3, acc1);
      }
    } else {
#pragma unroll
      for (int i = 0; i < 16; ++i) {
        float wbase = (u1[i] >= thr1) ? __expf(invOrd(u1[i]) - m1) : 0.f;
        for (int src = 0; src < 64; ++src) {
          float wgt = __shfl(wbase, src);
          if (wgt != 0.f)
            acc1 = fmaf(wgt, Vbh[(size_t)(src + 64*i)*Dn + lane], acc1);
        }
      }
    }
  }

  int b = bh / Hn, h = bh - b*Hn;
  out[((size_t)(b*Nn + qbase + r0))*Cn + h*Dn + lane] = acc0 * (1.0f / Z0);
  out[((size_t)(b*Nn + qbase + r1))*Cn + h*Dn + lane] = acc1 * (1.0f / Z1);
}

extern "C" void kernel_launch(void* const* d_in, const int* in_sizes, int n_in,
                              void* d_out, int out_size, void* d_ws, size_t ws_size,
                              hipStream_t stream) {
  const float* x      = (const float*)d_in[0];
  const float* qkv_w  = (const float*)d_in[1];
  const float* qkv_b  = (const float*)d_in[2];
  const float* proj_w = (const float*)d_in[3];
  const float* proj_b = (const float*)d_in[4];
  const int*   kptr   = (const int*)d_in[5];

  const size_t sz  = (size_t)Bn * Hn * Nn * Dn;  // 6291456 (== 8192*768)
  const size_t XSZ = (size_t)8192 * 768;         // X plane elems (== sz)
  const size_t WSZ = (size_t)2304 * 768;         // W plane elems
  _Float16* qh = (_Float16*)d_ws;                // split-fp16 q/k planes
  _Float16* ql = qh + sz;
  _Float16* kh = ql + sz;
  _Float16* kl = kh + sz;
  float* vbuf  = (float*)(kl + sz);
  _Float16* xh = (_Float16*)(vbuf + sz);         // X planes; region reused
  _Float16* xl = xh + XSZ;                       //   as att after qkv reads
  float* att   = (float*)xh;                     // (B,N,C) == Xh+Xl bytes
  _Float16* wh = xl + XSZ;                       // W planes
  _Float16* wl = wh + WSZ;
  float* outp  = (float*)d_out;

  split_planes<<<dim3(2048), 256, 0, stream>>>(x, qkv_w, xh, xl, wh, wl);
  qkv_gemm_mfma<<<dim3(36*64), 256, 0, stream>>>(xh, xl, wh, wl, qkv_b,
                                                 qh, ql, kh, kl, vbuf);
  attn_kernel<<<dim3(Bn*Hn*(Nn/16)), 512, 0, stream>>>(qh, ql, kh, kl,
                                                       vbuf, kptr, att);
  proj_mfma<<<dim3(12*64), 256, 0, stream>>>(att, proj_w, proj_b, outp);
}